// Round 4
// baseline (503.392 us; speedup 1.0000x reference)
//
#include <hip/hip_runtime.h>
#include <math.h>

#define NB 16        // batch
#define CH 256       // hidden
#define NH 4
#define KC 64
#define TTT 2048
#define TSS 512

typedef __attribute__((ext_vector_type(8))) short bf16x8;
typedef __attribute__((ext_vector_type(4))) float f32x4;

__device__ inline short f2bf(float x) {   // round-to-nearest-even bf16
  unsigned u = __float_as_uint(x);
  u += 0x7fffu + ((u >> 16) & 1u);
  return (short)(u >> 16);
}
__device__ inline unsigned pack2bf(float a, float b) {
  return (unsigned)(unsigned short)f2bf(a) | ((unsigned)(unsigned short)f2bf(b) << 16);
}

// fast sincos, input in revolutions (fract-reduced to [0,1), inside HW range)
__device__ inline void fast_sincos_rev(float rev, float* sn, float* cs) {
  float fr = rev - truncf(rev);
#if __has_builtin(__builtin_amdgcn_sinf)
  *sn = __builtin_amdgcn_sinf(fr);
  *cs = __builtin_amdgcn_cosf(fr);
#else
  float ang = fr * 6.28318530717958648f;
  *sn = __sinf(ang);
  *cs = __cosf(ang);
#endif
}

#define INV2PI 0.15915494309189535f
#define ROPE_C 0.28782313662425572f   // ln(10000)*2/64

// ---------------------------------------------------------------------------
// Templated tiled GEMM: Yn[b] = Wn @ X[b] + bn  (fp32; used for K/V + folds)
// ---------------------------------------------------------------------------
template <int TN, int NOUT>
__global__ __launch_bounds__(256) void gemm_v2(
    const float* __restrict__ W0, const float* __restrict__ b0,
    const float* __restrict__ W1, const float* __restrict__ b1,
    const float* __restrict__ X, float* __restrict__ Y0, float* __restrict__ Y1,
    int K, int T) {
  constexpr int TT = 16 * TN;
  constexpr int TQ = TT / 4;
  constexpr int PB = (32 * TQ) / 256;
  const int t0 = blockIdx.x * TT;
  const int m0 = blockIdx.y * 64;
  const int b  = blockIdx.z;
  const int tid = threadIdx.x;
  const int tx = tid & 15, ty = tid >> 4;

  __shared__ float As[NOUT][32][68];
  __shared__ float Bs[32][TT + 4];

  const float* Xb = X + (size_t)b * K * T;
  float acc[NOUT][4][TN];
#pragma unroll
  for (int n = 0; n < NOUT; ++n)
#pragma unroll
    for (int i = 0; i < 4; ++i)
#pragma unroll
      for (int u = 0; u < TN; ++u) acc[n][i][u] = 0.f;

  const int am = tid >> 2, akq = tid & 3;

  for (int k0 = 0; k0 < K; k0 += 32) {
#pragma unroll
    for (int n = 0; n < NOUT; ++n) {
      const float* Wn = (n == 0) ? W0 : W1;
      float4 a0 = *(const float4*)&Wn[(size_t)(m0 + am) * K + k0 + 4 * akq];
      float4 a1 = *(const float4*)&Wn[(size_t)(m0 + am) * K + k0 + 16 + 4 * akq];
      As[n][4 * akq + 0][am] = a0.x; As[n][4 * akq + 1][am] = a0.y;
      As[n][4 * akq + 2][am] = a0.z; As[n][4 * akq + 3][am] = a0.w;
      As[n][16 + 4 * akq + 0][am] = a1.x; As[n][16 + 4 * akq + 1][am] = a1.y;
      As[n][16 + 4 * akq + 2][am] = a1.z; As[n][16 + 4 * akq + 3][am] = a1.w;
    }
#pragma unroll
    for (int p = 0; p < PB; ++p) {
      int idx = tid + p * 256;
      int t4 = idx & (TQ - 1), k = idx / TQ;
      *(float4*)&Bs[k][4 * t4] = *(const float4*)&Xb[(size_t)(k0 + k) * T + t0 + 4 * t4];
    }
    __syncthreads();
#pragma unroll
    for (int kk = 0; kk < 32; ++kk) {
      float4 av[NOUT];
#pragma unroll
      for (int n = 0; n < NOUT; ++n) av[n] = *(const float4*)&As[n][kk][4 * ty];
      float4 bv[TN / 4];
#pragma unroll
      for (int g = 0; g < TN / 4; ++g) bv[g] = *(const float4*)&Bs[kk][4 * tx + 64 * g];
#pragma unroll
      for (int n = 0; n < NOUT; ++n) {
        const float a4[4] = {av[n].x, av[n].y, av[n].z, av[n].w};
#pragma unroll
        for (int i = 0; i < 4; ++i)
#pragma unroll
          for (int g = 0; g < TN / 4; ++g) {
            acc[n][i][4 * g + 0] += a4[i] * bv[g].x;
            acc[n][i][4 * g + 1] += a4[i] * bv[g].y;
            acc[n][i][4 * g + 2] += a4[i] * bv[g].z;
            acc[n][i][4 * g + 3] += a4[i] * bv[g].w;
          }
      }
    }
    __syncthreads();
  }
#pragma unroll
  for (int n = 0; n < NOUT; ++n) {
    float* Yn = (n == 0) ? Y0 : Y1;
    const float* bn = (n == 0) ? b0 : b1;
#pragma unroll
    for (int i = 0; i < 4; ++i) {
      int row = m0 + 4 * ty + i;
      float bi = bn[row];
#pragma unroll
      for (int g = 0; g < TN / 4; ++g) {
        float4 ov;
        ov.x = acc[n][i][4 * g + 0] + bi; ov.y = acc[n][i][4 * g + 1] + bi;
        ov.z = acc[n][i][4 * g + 2] + bi; ov.w = acc[n][i][4 * g + 3] + bi;
        *(float4*)&Yn[((size_t)b * 256 + row) * T + t0 + 4 * tx + 64 * g] = ov;
      }
    }
  }
}

// ---------------------------------------------------------------------------
// gemm_q_rope: q = Wq @ x + bq, then fused RoPE + bf16 + transpose epilogue.
// Writes Q as MFMA A-fragments: [bh][t][64ch] bf16. Grid (16, NH, NB).
// ---------------------------------------------------------------------------
__global__ __launch_bounds__(256) void gemm_q_rope(
    const float* __restrict__ W, const float* __restrict__ bias,
    const float* __restrict__ X, short* __restrict__ qbf) {
  const int t0 = blockIdx.x * 128;
  const int h  = blockIdx.y;
  const int b  = blockIdx.z;
  const int m0 = h * 64;
  const int tid = threadIdx.x;
  const int tx = tid & 15, ty = tid >> 4;

  __shared__ __align__(16) char gsm[34048];
  float* As = (float*)gsm;             // [32][68]
  float* Bs = (float*)(gsm + 8704);    // [32][132]
  float* Ep = (float*)gsm;             // [64][133] (epilogue reuse)

  const float* Xb = X + (size_t)b * 256 * TTT;
  float acc[4][8];
#pragma unroll
  for (int i = 0; i < 4; ++i)
#pragma unroll
    for (int u = 0; u < 8; ++u) acc[i][u] = 0.f;

  const int am = tid >> 2, akq = tid & 3;

  for (int k0 = 0; k0 < 256; k0 += 32) {
    {
      float4 a0 = *(const float4*)&W[(size_t)(m0 + am) * 256 + k0 + 4 * akq];
      float4 a1 = *(const float4*)&W[(size_t)(m0 + am) * 256 + k0 + 16 + 4 * akq];
      As[(4 * akq + 0) * 68 + am] = a0.x; As[(4 * akq + 1) * 68 + am] = a0.y;
      As[(4 * akq + 2) * 68 + am] = a0.z; As[(4 * akq + 3) * 68 + am] = a0.w;
      As[(16 + 4 * akq + 0) * 68 + am] = a1.x; As[(16 + 4 * akq + 1) * 68 + am] = a1.y;
      As[(16 + 4 * akq + 2) * 68 + am] = a1.z; As[(16 + 4 * akq + 3) * 68 + am] = a1.w;
    }
#pragma unroll
    for (int p = 0; p < 4; ++p) {
      int idx = tid + p * 256;
      int t4 = idx & 31, k = idx >> 5;
      *(float4*)&Bs[k * 132 + 4 * t4] = *(const float4*)&Xb[(size_t)(k0 + k) * TTT + t0 + 4 * t4];
    }
    __syncthreads();
#pragma unroll
    for (int kk = 0; kk < 32; ++kk) {
      float4 av = *(const float4*)&As[kk * 68 + 4 * ty];
      float4 bv0 = *(const float4*)&Bs[kk * 132 + 4 * tx];
      float4 bv1 = *(const float4*)&Bs[kk * 132 + 4 * tx + 64];
      const float a4[4] = {av.x, av.y, av.z, av.w};
#pragma unroll
      for (int i = 0; i < 4; ++i) {
        acc[i][0] += a4[i] * bv0.x; acc[i][1] += a4[i] * bv0.y;
        acc[i][2] += a4[i] * bv0.z; acc[i][3] += a4[i] * bv0.w;
        acc[i][4] += a4[i] * bv1.x; acc[i][5] += a4[i] * bv1.y;
        acc[i][6] += a4[i] * bv1.z; acc[i][7] += a4[i] * bv1.w;
      }
    }
    __syncthreads();
  }

  // ---- stage acc (+bias) into Ep [64 rows][128 cols], stride 133 ----
#pragma unroll
  for (int i = 0; i < 4; ++i) {
    int row = 4 * ty + i;
    float bi = bias[m0 + row];
#pragma unroll
    for (int e = 0; e < 4; ++e) {
      Ep[row * 133 + 4 * tx + e]      = acc[i][e] + bi;
      Ep[row * 133 + 4 * tx + 64 + e] = acc[i][4 + e] + bi;
    }
  }
  __syncthreads();

  // ---- rope + bf16 + transposed write:  unit = (t, 8-ch block) ----
  const int cb = tid & 3;
  float invr[8];
#pragma unroll
  for (int e = 0; e < 8; ++e)
    invr[e] = __expf(-(float)(cb * 8 + e) * ROPE_C) * INV2PI;

  const size_t qoff = ((size_t)(b * NH + h) * TTT + t0) * 64;
#pragma unroll
  for (int p = 0; p < 2; ++p) {
    int idx = tid + p * 256;
    int t = idx >> 2;                    // 0..127
    float tg = (float)(t0 + t);
    float oa[8], oc[8];
#pragma unroll
    for (int e = 0; e < 8; ++e) {
      int j = cb * 8 + e;
      float a = Ep[j * 133 + t];
      float c = Ep[(j + 32) * 133 + t];
      float sn, cs;
      fast_sincos_rev(tg * invr[e], &sn, &cs);
      oa[e] = a * cs - c * sn;
      oc[e] = c * cs + a * sn;
    }
    short* dst = qbf + qoff + (size_t)t * 64 + cb * 8;
    *(uint4*)dst = make_uint4(pack2bf(oa[0], oa[1]), pack2bf(oa[2], oa[3]),
                              pack2bf(oa[4], oa[5]), pack2bf(oa[6], oa[7]));
    *(uint4*)(dst + 32) = make_uint4(pack2bf(oc[0], oc[1]), pack2bf(oc[2], oc[3]),
                                     pack2bf(oc[4], oc[5]), pack2bf(oc[6], oc[7]));
  }
}

// ---------------------------------------------------------------------------
// Bias folding (unchanged / passing)
// ---------------------------------------------------------------------------
__global__ __launch_bounds__(256) void bias_fold(
    const float* __restrict__ wk, const float* __restrict__ bk,
    const float* __restrict__ wv, const float* __restrict__ bv,
    const float* __restrict__ bcond,
    const float* __restrict__ wfilm, const float* __restrict__ bo,
    const float* __restrict__ bfilm,
    float* __restrict__ bk2, float* __restrict__ bv2, float* __restrict__ bf2) {
  int g = blockIdx.x * 256 + threadIdx.x;
  if (g < 256) {
    float s = bk[g];
    for (int k = 0; k < 256; ++k) s += wk[g * 256 + k] * bcond[k];
    bk2[g] = s;
  } else if (g < 512) {
    int m = g - 256;
    float s = bv[m];
    for (int k = 0; k < 256; ++k) s += wv[m * 256 + k] * bcond[k];
    bv2[m] = s;
  } else if (g < 1024) {
    int m = g - 512;
    float s = bfilm[m];
    for (int k = 0; k < 256; ++k) s += wfilm[m * 256 + k] * bo[k];
    bf2[m] = s;
  }
}

// ---------------------------------------------------------------------------
// fp32 -> bf16 bulk convert (for folded film weights)
// ---------------------------------------------------------------------------
__global__ __launch_bounds__(256) void cvt_bf16(
    const float* __restrict__ src, short* __restrict__ dst, int n) {
  int i = (blockIdx.x * 256 + threadIdx.x) * 8;
  if (i < n) {
    float4 a = *(const float4*)&src[i];
    float4 c = *(const float4*)&src[i + 4];
    uint4 w;
    w.x = pack2bf(a.x, a.y); w.y = pack2bf(a.z, a.w);
    w.z = pack2bf(c.x, c.y); w.w = pack2bf(c.z, c.w);
    *(uint4*)&dst[i] = w;
  }
}

// ---------------------------------------------------------------------------
// kvprep: K -> rope -> bf16 transposed [bh][s][64ch];  V -> bf16 [bh][64ch][s]
// Grid (TSS/64, NH, NB), block 256. Fast HW trig (revolutions).
// ---------------------------------------------------------------------------
__global__ __launch_bounds__(256) void kvprep(
    const float* __restrict__ kf32, const float* __restrict__ vf32,
    short* __restrict__ kbf, short* __restrict__ vbf) {
  const int s0 = blockIdx.x * 64;
  const int h = blockIdx.y, b = blockIdx.z;
  const int bh = b * NH + h;
  const int tid = threadIdx.x;
  const float* kb = kf32 + ((size_t)(b * CH + h * KC)) * TSS;
  const float* vb = vf32 + ((size_t)(b * CH + h * KC)) * TSS;

  __shared__ float Kls[64 * 68];

  // stage K chunk with fused RoPE (pairs j, j+32)
#pragma unroll
  for (int p = 0; p < 2; ++p) {
    int idx = tid + p * 256;          // 0..511
    int j = idx >> 4, s4 = idx & 15;  // j 0..31
    float4 ka = *(const float4*)&kb[(size_t)j * TSS + s0 + 4 * s4];
    float4 kc = *(const float4*)&kb[(size_t)(j + 32) * TSS + s0 + 4 * s4];
    float invr = __expf(-(float)j * ROPE_C) * INV2PI;
    const float av[4] = {ka.x, ka.y, ka.z, ka.w};
    const float cv[4] = {kc.x, kc.y, kc.z, kc.w};
    float oa[4], oc[4];
#pragma unroll
    for (int e = 0; e < 4; ++e) {
      float sn, cs;
      fast_sincos_rev((float)(s0 + 4 * s4 + e) * invr, &sn, &cs);
      oa[e] = av[e] * cs - cv[e] * sn;
      oc[e] = cv[e] * cs + av[e] * sn;
    }
    *(float4*)&Kls[j * 68 + 4 * s4] = make_float4(oa[0], oa[1], oa[2], oa[3]);
    *(float4*)&Kls[(j + 32) * 68 + 4 * s4] = make_float4(oc[0], oc[1], oc[2], oc[3]);
  }
  __syncthreads();

  // transpose K out: thread -> (s, 16-ch group)
  {
    int s = tid >> 2, g = tid & 3;
    unsigned ow[8];
#pragma unroll
    for (int hlf = 0; hlf < 8; ++hlf) {
      int ch = g * 16 + hlf * 2;
      ow[hlf] = pack2bf(Kls[ch * 68 + s], Kls[(ch + 1) * 68 + s]);
    }
    short* dst = kbf + ((size_t)bh * TSS + s0 + s) * 64 + g * 16;
    *(uint4*)dst = make_uint4(ow[0], ow[1], ow[2], ow[3]);
    *(uint4*)(dst + 8) = make_uint4(ow[4], ow[5], ow[6], ow[7]);
  }

  // V straight cvt
#pragma unroll
  for (int p = 0; p < 4; ++p) {
    int idx = tid + p * 256;          // 0..1023
    int ch = idx >> 4, s4 = idx & 15;
    float4 v = *(const float4*)&vb[(size_t)ch * TSS + s0 + 4 * s4];
    uint2 w2 = make_uint2(pack2bf(v.x, v.y), pack2bf(v.z, v.w));
    *(uint2*)(vbf + ((size_t)bh * KC + ch) * TSS + s0 + 4 * s4) = w2;
  }
}

// ---------------------------------------------------------------------------
// attn_mfma: barrier-free bf16 MFMA attention. 256 thr / 4 waves, 64 t-rows
// per block; each wave owns 16 t. NO K/V LDS staging: K+V are 8 MB total and
// L2/L3-resident (common-mistake #7: staging cache-fit data is overhead) --
// frags are loaded straight from global. Every K/V cache line touched is
// fully consumed by the loading wave (quads cover the full 128-B row), so
// there is no over-fetch. LDS holds only the wave-private P tiles (16 KB,
// aliased by the 8-KB O-stage at the epilogue) -> no __syncthreads() in the
// whole main loop; latency hidden by ~24 waves/CU.
// Grid 1D 2048 with bijective XCD swizzle: each XCD's co-resident blocks
// span 8 (b,h) pairs -> K/V working set ~1 MB << 4 MB L2.
// Layouts (m89/m120-verified): A [m=lane&15][k=quad*8+j]; B same;
// C/D row=quad*4+reg, col=lane&15.
// ---------------------------------------------------------------------------
__global__ __launch_bounds__(256, 6) void attn_mfma(
    const short* __restrict__ qbf, const short* __restrict__ kbf,
    const short* __restrict__ vbf, const float* __restrict__ cond_mask,
    short* __restrict__ obuf) {
  // XCD swizzle: 2048 blocks, 8 XCDs, 256 per XCD (bijective: 2048%8==0)
  const int wg = blockIdx.x;
  const int lin = (wg & 7) * 256 + (wg >> 3);
  const int tblk = lin & 31;          // 32 t-blocks of 64
  const int h = (lin >> 5) & 3;
  const int b = lin >> 7;
  const int t0 = tblk * 64;
  const int bh = b * NH + h;
  const int tid = threadIdx.x;
  const int w = tid >> 6, lane = tid & 63;
  const int quad = lane >> 4, l15 = lane & 15;

  __shared__ __align__(16) short Ps[64 * 128];  // [t][s] wave-private rows, 16 KB
  // epilogue aliases the first 8 KB as Os[64][64]

  // ---- Q A-frags straight from global ----
  const short* qb = qbf + ((size_t)bh * TTT + t0) * 64;
  const int trow_l = w * 16 + l15;
  bf16x8 qf0 = *(const bf16x8*)&qb[(size_t)trow_l * 64 + quad * 8];
  bf16x8 qf1 = *(const bf16x8*)&qb[(size_t)trow_l * 64 + 32 + quad * 8];

  f32x4 acc_o[4];
#pragma unroll
  for (int n = 0; n < 4; ++n) acc_o[n] = (f32x4){0.f, 0.f, 0.f, 0.f};
  float den[4] = {0.f, 0.f, 0.f, 0.f};

  const float* cm = cond_mask + (size_t)b * TSS;
  const short* kbase = kbf + (size_t)bh * TSS * 64;
  const short* vbase = vbf + (size_t)bh * KC * TSS;

  for (int s0 = 0; s0 < TSS; s0 += 128) {
    // ---- QK^T + softmax + P write (P rows wave-private; no barriers) ----
#pragma unroll
    for (int n0 = 0; n0 < 8; ++n0) {
      int srow = s0 + n0 * 16 + l15;
      bf16x8 kf0 = *(const bf16x8*)&kbase[(size_t)srow * 64 + quad * 8];
      bf16x8 kf1 = *(const bf16x8*)&kbase[(size_t)srow * 64 + 32 + quad * 8];
      f32x4 acc = (f32x4){0.f, 0.f, 0.f, 0.f};
      acc = __builtin_amdgcn_mfma_f32_16x16x32_bf16(qf0, kf0, acc, 0, 0, 0);
      acc = __builtin_amdgcn_mfma_f32_16x16x32_bf16(qf1, kf1, acc, 0, 0, 0);
      float mk = (cm[srow] != 0.f) ? 1.f : 0.f;
      int sblk = n0 * 2 + (l15 >> 3);
      int slow = l15 & 7;
#pragma unroll
      for (int r = 0; r < 4; ++r) {
        float e = __expf(acc[r] * 0.125f) * mk;
        den[r] += e;
        int trow = w * 16 + quad * 4 + r;
        Ps[trow * 128 + 8 * (sblk ^ (trow & 7)) + slow] = f2bf(e);
      }
    }

    // ---- PV: O += P V  (P from wave-private LDS, V straight from global) ----
    {
      int trow = w * 16 + l15;
#pragma unroll
      for (int kt = 0; kt < 4; ++kt) {
        bf16x8 pf = *(const bf16x8*)&Ps[trow * 128 + 8 * ((kt * 4 + quad) ^ (trow & 7))];
#pragma unroll
        for (int n0 = 0; n0 < 4; ++n0) {
          int ch = n0 * 16 + l15;
          bf16x8 vf = *(const bf16x8*)&vbase[(size_t)ch * TSS + s0 + (kt * 4 + quad) * 8];
          acc_o[n0] = __builtin_amdgcn_mfma_f32_16x16x32_bf16(pf, vf, acc_o[n0], 0, 0, 0);
        }
      }
    }
  }

  // ---- denominators: reduce over the 16 s-lanes within each quad ----
  float rd[4];
#pragma unroll
  for (int r = 0; r < 4; ++r) {
    float d = den[r];
#pragma unroll
    for (int off = 1; off < 16; off <<= 1) d += __shfl_xor(d, off, 16);
    rd[r] = 1.f / fmaxf(d, 1e-30f);
  }

  // ---- O epilogue: bf16, t-major. Stage [64t][64ch] in LDS (aliases Ps). ----
  __syncthreads();                 // all waves done with their P reads
  short* Os = Ps;                  // [t*64 + ch]  64x64 bf16 (8 KB)
#pragma unroll
  for (int n0 = 0; n0 < 4; ++n0)
#pragma unroll
    for (int r = 0; r < 4; ++r) {
      int ch = n0 * 16 + l15;
      int trow = w * 16 + quad * 4 + r;
      Os[trow * 64 + ch] = f2bf(acc_o[n0][r] * rd[r]);
    }
  __syncthreads();

  short* ob = obuf + ((size_t)b * TTT + t0) * CH + h * KC;
#pragma unroll
  for (int p = 0; p < 2; ++p) {
    int idx = tid + p * 256;         // 0..511 chunks of 8 shorts
    int t = idx >> 3, c8 = idx & 7;
    *(uint4*)&ob[(size_t)t * CH + c8 * 8] = *(const uint4*)&Os[t * 64 + c8 * 8];
  }
}

// ---------------------------------------------------------------------------
// film_mfma: gb = wf2(bf16) @ Ybf(bf16, [b][t][256]) + bf2;
//            out = (x*gamma + beta) * xmask.   (unchanged / passing)
// ---------------------------------------------------------------------------
__global__ __launch_bounds__(256) void film_mfma(
    const short* __restrict__ wfbf, const float* __restrict__ bf2,
    const short* __restrict__ ybf, const float* __restrict__ X,
    const float* __restrict__ xmask, float* __restrict__ out) {
  const int t0 = blockIdx.x * 64;
  const int b = blockIdx.y;
  const int tid = threadIdx.x;
  const int w = tid >> 6, lane = tid & 63;
  const int quad = lane >> 4, l15 = lane & 15;

  __shared__ __align__(16) short Ys[64 * 256];   // [t][ch] bf16, swizzled

  const short* yb = ybf + ((size_t)b * TTT + t0) * CH;
#pragma unroll
  for (int p = 0; p < 8; ++p) {
    int idx = tid + p * 256;          // 0..2047 chunks of 8 shorts
    int cb = idx & 31, tr = idx >> 5; // 32 chunks per row
    *(uint4*)&Ys[tr * 256 + 8 * (cb ^ (tr & 7))] =
        *(const uint4*)&yb[(size_t)tr * CH + 8 * cb];
  }
  __syncthreads();

  const int mbase = w * 64;
  f32x4 accg[4][4], accb[4][4];
#pragma unroll
  for (int mf = 0; mf < 4; ++mf)
#pragma unroll
    for (int nt = 0; nt < 4; ++nt) {
      accg[mf][nt] = (f32x4){0.f, 0.f, 0.f, 0.f};
      accb[mf][nt] = (f32x4){0.f, 0.f, 0.f, 0.f};
    }

#pragma unroll
  for (int k0 = 0; k0 < 256; k0 += 32) {
    const int cb0 = (k0 >> 3) + quad;
    bf16x8 bfr[4];
#pragma unroll
    for (int nt = 0; nt < 4; ++nt) {
      int tr = nt * 16 + l15;
      bfr[nt] = *(const bf16x8*)&Ys[tr * 256 + 8 * (cb0 ^ (tr & 7))];
    }
#pragma unroll
    for (int mf = 0; mf < 4; ++mf) {
      int rowg = mbase + mf * 16 + l15;
      bf16x8 ag = *(const bf16x8*)&wfbf[(size_t)rowg * 256 + k0 + quad * 8];
      bf16x8 ab = *(const bf16x8*)&wfbf[(size_t)(256 + rowg) * 256 + k0 + quad * 8];
#pragma unroll
      for (int nt = 0; nt < 4; ++nt) {
        accg[mf][nt] = __builtin_amdgcn_mfma_f32_16x16x32_bf16(ag, bfr[nt], accg[mf][nt], 0, 0, 0);
        accb[mf][nt] = __builtin_amdgcn_mfma_f32_16x16x32_bf16(ab, bfr[nt], accb[mf][nt], 0, 0, 0);
      }
    }
  }

  const float* xb = X + (size_t)b * CH * TTT + t0;
  const float* xm = xmask + (size_t)b * TTT + t0;
  float* ob = out + (size_t)b * CH * TTT + t0;
  float xmv[4];
#pragma unroll
  for (int nt = 0; nt < 4; ++nt) xmv[nt] = xm[nt * 16 + l15];

#pragma unroll
  for (int mf = 0; mf < 4; ++mf) {
#pragma unroll
    for (int r = 0; r < 4; ++r) {
      int row = mbase + mf * 16 + quad * 4 + r;   // C/D: m = quad*4+reg
      float bg = bf2[row];
      float bb = bf2[256 + row];
#pragma unroll
      for (int nt = 0; nt < 4; ++nt) {
        int t = nt * 16 + l15;                    // C/D: n = lane&15
        float g  = accg[mf][nt][r] + bg;
        float bt = accb[mf][nt][r] + bb;
        float xv = xb[(size_t)row * TTT + t];
        ob[(size_t)row * TTT + t] = (xv * g + bt) * xmv[nt];
      }
    }
  }
}

// ---------------------------------------------------------------------------
extern "C" void kernel_launch(void* const* d_in, const int* in_sizes, int n_in,
                              void* d_out, int out_size, void* d_ws, size_t ws_size,
                              hipStream_t stream) {
  const float* x           = (const float*)d_in[0];
  const float* x_mask      = (const float*)d_in[1];
  const float* cond_latent = (const float*)d_in[2];
  const float* cond_mask   = (const float*)d_in[3];
  const float* w_cond      = (const float*)d_in[4];
  const float* b_cond      = (const float*)d_in[5];
  const float* wq          = (const float*)d_in[6];
  const float* bq          = (const float*)d_in[7];
  const float* wk          = (const float*)d_in[8];
  const float* bk          = (const float*)d_in[9];
  const float* wv          = (const float*)d_in[10];
  const float* bv          = (const float*)d_in[11];
  const float* wo          = (const float*)d_in[12];
  const float* bo          = (const float*)d_in[13];
  const float* w_film      = (const float*)d_in[14];
  const float* b_film      = (const float*)d_in[15];
  float* out = (float*)d_out;

  float* ws = (float*)d_ws;
  float* k_buf = ws;                    // 2,097,152
  float* v_buf = k_buf + 2097152;       // 2,097,152
  float* wk2   = v_buf + 2097152;       // 131,072
  float* wv2   = wk2 + 131072;          // 131,072
  float* wf2   = wv2 + 131072;          // 131,072
  float* bk2   = wf2 + 131072;          // 256
  float* bv2   = bk2 + 256;             // 256
  float* bf2   = bv2 + 256;             // 512
  float* zbuf  = bf2 + 512;             // 512 zeros
  short* k_bf  = (short*)(zbuf + 512);  // 16*4*512*64 bf16
  short* v_bf  = k_bf + 2097152;        // 16*4*64*512 bf16
  short* wf2bf = v_bf + 2097152;        // 512*256 bf16
  short* q_bf  = wf2bf + 131072;        // 16*4*2048*64 bf16 (pre-roped Q frags)
  // attn output (bf16, [b][t][256]) reuses k_buf+v_buf region (free post-kvprep)
  short* o_bf  = (short*)k_buf;         // 16*2048*256 bf16 = 16 MB

  dim3 blk(256);

  hipMemsetAsync(zbuf, 0, 512 * sizeof(float), stream);

  // --- weight folding (tiny GEMMs, B=1) ---
  gemm_v2<4, 2><<<dim3(8, 4, 1), blk, 0, stream>>>(
      wk, zbuf, wv, zbuf, w_cond, wk2, wv2, 256, 512);
  gemm_v2<4, 1><<<dim3(4, 8, 1), blk, 0, stream>>>(
      w_film, zbuf, nullptr, nullptr, wo, wf2, nullptr, 256, 256);
  cvt_bf16<<<dim3(64), blk, 0, stream>>>(wf2, wf2bf, 131072);
  bias_fold<<<dim3(4), blk, 0, stream>>>(wk, bk, wv, bv, b_cond,
                                         w_film, bo, b_film, bk2, bv2, bf2);

  // --- main pipeline ---
  // Q GEMM with fused RoPE + bf16 + transpose epilogue
  gemm_q_rope<<<dim3(16, 4, 16), blk, 0, stream>>>(wq, bq, x, q_bf);
  gemm_v2<4, 2><<<dim3(8, 4, 16), blk, 0, stream>>>(
      wk2, bk2, wv2, bv2, cond_latent, k_buf, v_buf, 512, 512);
  // K rope + transpose + bf16; V bf16
  kvprep<<<dim3(8, 4, 16), blk, 0, stream>>>(k_buf, v_buf, k_bf, v_bf);
  // barrier-free MFMA attention (4 waves, 64 t per block; XCD-swizzled grid)
  attn_mfma<<<dim3(2048), blk, 0, stream>>>(q_bf, k_bf, v_bf, cond_mask, o_bf);
  // MFMA film + final output
  film_mfma<<<dim3(32, 16), blk, 0, stream>>>(wf2bf, bf2, o_bf, x, x_mask, out);
}

// Round 5
// 369.933 us; speedup vs baseline: 1.3608x; 1.3608x over previous
//
#include <hip/hip_runtime.h>
#include <math.h>

#define NB 16        // batch
#define CH 256       // hidden
#define NH 4
#define KC 64
#define TTT 2048
#define TSS 512

typedef __attribute__((ext_vector_type(8))) short bf16x8;
typedef __attribute__((ext_vector_type(4))) float f32x4;

__device__ inline short f2bf(float x) {   // round-to-nearest-even bf16
  unsigned u = __float_as_uint(x);
  u += 0x7fffu + ((u >> 16) & 1u);
  return (short)(u >> 16);
}
__device__ inline unsigned pack2bf(float a, float b) {
  return (unsigned)(unsigned short)f2bf(a) | ((unsigned)(unsigned short)f2bf(b) << 16);
}

// fast sincos, input in revolutions (fract-reduced to [0,1), inside HW range)
__device__ inline void fast_sincos_rev(float rev, float* sn, float* cs) {
  float fr = rev - truncf(rev);
#if __has_builtin(__builtin_amdgcn_sinf)
  *sn = __builtin_amdgcn_sinf(fr);
  *cs = __builtin_amdgcn_cosf(fr);
#else
  float ang = fr * 6.28318530717958648f;
  *sn = __sinf(ang);
  *cs = __cosf(ang);
#endif
}

#define INV2PI 0.15915494309189535f
#define ROPE_C 0.28782313662425572f   // ln(10000)*2/64

// ---------------------------------------------------------------------------
// Templated tiled GEMM: Yn[b] = Wn @ X[b] + bn  (fp32; used for K/V + folds)
// ---------------------------------------------------------------------------
template <int TN, int NOUT>
__global__ __launch_bounds__(256) void gemm_v2(
    const float* __restrict__ W0, const float* __restrict__ b0,
    const float* __restrict__ W1, const float* __restrict__ b1,
    const float* __restrict__ X, float* __restrict__ Y0, float* __restrict__ Y1,
    int K, int T) {
  constexpr int TT = 16 * TN;
  constexpr int TQ = TT / 4;
  constexpr int PB = (32 * TQ) / 256;
  const int t0 = blockIdx.x * TT;
  const int m0 = blockIdx.y * 64;
  const int b  = blockIdx.z;
  const int tid = threadIdx.x;
  const int tx = tid & 15, ty = tid >> 4;

  __shared__ float As[NOUT][32][68];
  __shared__ float Bs[32][TT + 4];

  const float* Xb = X + (size_t)b * K * T;
  float acc[NOUT][4][TN];
#pragma unroll
  for (int n = 0; n < NOUT; ++n)
#pragma unroll
    for (int i = 0; i < 4; ++i)
#pragma unroll
      for (int u = 0; u < TN; ++u) acc[n][i][u] = 0.f;

  const int am = tid >> 2, akq = tid & 3;

  for (int k0 = 0; k0 < K; k0 += 32) {
#pragma unroll
    for (int n = 0; n < NOUT; ++n) {
      const float* Wn = (n == 0) ? W0 : W1;
      float4 a0 = *(const float4*)&Wn[(size_t)(m0 + am) * K + k0 + 4 * akq];
      float4 a1 = *(const float4*)&Wn[(size_t)(m0 + am) * K + k0 + 16 + 4 * akq];
      As[n][4 * akq + 0][am] = a0.x; As[n][4 * akq + 1][am] = a0.y;
      As[n][4 * akq + 2][am] = a0.z; As[n][4 * akq + 3][am] = a0.w;
      As[n][16 + 4 * akq + 0][am] = a1.x; As[n][16 + 4 * akq + 1][am] = a1.y;
      As[n][16 + 4 * akq + 2][am] = a1.z; As[n][16 + 4 * akq + 3][am] = a1.w;
    }
#pragma unroll
    for (int p = 0; p < PB; ++p) {
      int idx = tid + p * 256;
      int t4 = idx & (TQ - 1), k = idx / TQ;
      *(float4*)&Bs[k][4 * t4] = *(const float4*)&Xb[(size_t)(k0 + k) * T + t0 + 4 * t4];
    }
    __syncthreads();
#pragma unroll
    for (int kk = 0; kk < 32; ++kk) {
      float4 av[NOUT];
#pragma unroll
      for (int n = 0; n < NOUT; ++n) av[n] = *(const float4*)&As[n][kk][4 * ty];
      float4 bv[TN / 4];
#pragma unroll
      for (int g = 0; g < TN / 4; ++g) bv[g] = *(const float4*)&Bs[kk][4 * tx + 64 * g];
#pragma unroll
      for (int n = 0; n < NOUT; ++n) {
        const float a4[4] = {av[n].x, av[n].y, av[n].z, av[n].w};
#pragma unroll
        for (int i = 0; i < 4; ++i)
#pragma unroll
          for (int g = 0; g < TN / 4; ++g) {
            acc[n][i][4 * g + 0] += a4[i] * bv[g].x;
            acc[n][i][4 * g + 1] += a4[i] * bv[g].y;
            acc[n][i][4 * g + 2] += a4[i] * bv[g].z;
            acc[n][i][4 * g + 3] += a4[i] * bv[g].w;
          }
      }
    }
    __syncthreads();
  }
#pragma unroll
  for (int n = 0; n < NOUT; ++n) {
    float* Yn = (n == 0) ? Y0 : Y1;
    const float* bn = (n == 0) ? b0 : b1;
#pragma unroll
    for (int i = 0; i < 4; ++i) {
      int row = m0 + 4 * ty + i;
      float bi = bn[row];
#pragma unroll
      for (int g = 0; g < TN / 4; ++g) {
        float4 ov;
        ov.x = acc[n][i][4 * g + 0] + bi; ov.y = acc[n][i][4 * g + 1] + bi;
        ov.z = acc[n][i][4 * g + 2] + bi; ov.w = acc[n][i][4 * g + 3] + bi;
        *(float4*)&Yn[((size_t)b * 256 + row) * T + t0 + 4 * tx + 64 * g] = ov;
      }
    }
  }
}

// ---------------------------------------------------------------------------
// gemm_q_rope: q = Wq @ x + bq, then fused RoPE + bf16 + transpose epilogue.
// Writes Q as MFMA A-fragments: [bh][t][64ch] bf16. Grid (16, NH, NB).
// ---------------------------------------------------------------------------
__global__ __launch_bounds__(256) void gemm_q_rope(
    const float* __restrict__ W, const float* __restrict__ bias,
    const float* __restrict__ X, short* __restrict__ qbf) {
  const int t0 = blockIdx.x * 128;
  const int h  = blockIdx.y;
  const int b  = blockIdx.z;
  const int m0 = h * 64;
  const int tid = threadIdx.x;
  const int tx = tid & 15, ty = tid >> 4;

  __shared__ __align__(16) char gsm[34048];
  float* As = (float*)gsm;             // [32][68]
  float* Bs = (float*)(gsm + 8704);    // [32][132]
  float* Ep = (float*)gsm;             // [64][133] (epilogue reuse)

  const float* Xb = X + (size_t)b * 256 * TTT;
  float acc[4][8];
#pragma unroll
  for (int i = 0; i < 4; ++i)
#pragma unroll
    for (int u = 0; u < 8; ++u) acc[i][u] = 0.f;

  const int am = tid >> 2, akq = tid & 3;

  for (int k0 = 0; k0 < 256; k0 += 32) {
    {
      float4 a0 = *(const float4*)&W[(size_t)(m0 + am) * 256 + k0 + 4 * akq];
      float4 a1 = *(const float4*)&W[(size_t)(m0 + am) * 256 + k0 + 16 + 4 * akq];
      As[(4 * akq + 0) * 68 + am] = a0.x; As[(4 * akq + 1) * 68 + am] = a0.y;
      As[(4 * akq + 2) * 68 + am] = a0.z; As[(4 * akq + 3) * 68 + am] = a0.w;
      As[(16 + 4 * akq + 0) * 68 + am] = a1.x; As[(16 + 4 * akq + 1) * 68 + am] = a1.y;
      As[(16 + 4 * akq + 2) * 68 + am] = a1.z; As[(16 + 4 * akq + 3) * 68 + am] = a1.w;
    }
#pragma unroll
    for (int p = 0; p < 4; ++p) {
      int idx = tid + p * 256;
      int t4 = idx & 31, k = idx >> 5;
      *(float4*)&Bs[k * 132 + 4 * t4] = *(const float4*)&Xb[(size_t)(k0 + k) * TTT + t0 + 4 * t4];
    }
    __syncthreads();
#pragma unroll
    for (int kk = 0; kk < 32; ++kk) {
      float4 av = *(const float4*)&As[kk * 68 + 4 * ty];
      float4 bv0 = *(const float4*)&Bs[kk * 132 + 4 * tx];
      float4 bv1 = *(const float4*)&Bs[kk * 132 + 4 * tx + 64];
      const float a4[4] = {av.x, av.y, av.z, av.w};
#pragma unroll
      for (int i = 0; i < 4; ++i) {
        acc[i][0] += a4[i] * bv0.x; acc[i][1] += a4[i] * bv0.y;
        acc[i][2] += a4[i] * bv0.z; acc[i][3] += a4[i] * bv0.w;
        acc[i][4] += a4[i] * bv1.x; acc[i][5] += a4[i] * bv1.y;
        acc[i][6] += a4[i] * bv1.z; acc[i][7] += a4[i] * bv1.w;
      }
    }
    __syncthreads();
  }

  // ---- stage acc (+bias) into Ep [64 rows][128 cols], stride 133 ----
#pragma unroll
  for (int i = 0; i < 4; ++i) {
    int row = 4 * ty + i;
    float bi = bias[m0 + row];
#pragma unroll
    for (int e = 0; e < 4; ++e) {
      Ep[row * 133 + 4 * tx + e]      = acc[i][e] + bi;
      Ep[row * 133 + 4 * tx + 64 + e] = acc[i][4 + e] + bi;
    }
  }
  __syncthreads();

  // ---- rope + bf16 + transposed write:  unit = (t, 8-ch block) ----
  const int cb = tid & 3;
  float invr[8];
#pragma unroll
  for (int e = 0; e < 8; ++e)
    invr[e] = __expf(-(float)(cb * 8 + e) * ROPE_C) * INV2PI;

  const size_t qoff = ((size_t)(b * NH + h) * TTT + t0) * 64;
#pragma unroll
  for (int p = 0; p < 2; ++p) {
    int idx = tid + p * 256;
    int t = idx >> 2;                    // 0..127
    float tg = (float)(t0 + t);
    float oa[8], oc[8];
#pragma unroll
    for (int e = 0; e < 8; ++e) {
      int j = cb * 8 + e;
      float a = Ep[j * 133 + t];
      float c = Ep[(j + 32) * 133 + t];
      float sn, cs;
      fast_sincos_rev(tg * invr[e], &sn, &cs);
      oa[e] = a * cs - c * sn;
      oc[e] = c * cs + a * sn;
    }
    short* dst = qbf + qoff + (size_t)t * 64 + cb * 8;
    *(uint4*)dst = make_uint4(pack2bf(oa[0], oa[1]), pack2bf(oa[2], oa[3]),
                              pack2bf(oa[4], oa[5]), pack2bf(oa[6], oa[7]));
    *(uint4*)(dst + 32) = make_uint4(pack2bf(oc[0], oc[1]), pack2bf(oc[2], oc[3]),
                                     pack2bf(oc[4], oc[5]), pack2bf(oc[6], oc[7]));
  }
}

// ---------------------------------------------------------------------------
// Bias folding (unchanged / passing)
// ---------------------------------------------------------------------------
__global__ __launch_bounds__(256) void bias_fold(
    const float* __restrict__ wk, const float* __restrict__ bk,
    const float* __restrict__ wv, const float* __restrict__ bv,
    const float* __restrict__ bcond,
    const float* __restrict__ wfilm, const float* __restrict__ bo,
    const float* __restrict__ bfilm,
    float* __restrict__ bk2, float* __restrict__ bv2, float* __restrict__ bf2) {
  int g = blockIdx.x * 256 + threadIdx.x;
  if (g < 256) {
    float s = bk[g];
    for (int k = 0; k < 256; ++k) s += wk[g * 256 + k] * bcond[k];
    bk2[g] = s;
  } else if (g < 512) {
    int m = g - 256;
    float s = bv[m];
    for (int k = 0; k < 256; ++k) s += wv[m * 256 + k] * bcond[k];
    bv2[m] = s;
  } else if (g < 1024) {
    int m = g - 512;
    float s = bfilm[m];
    for (int k = 0; k < 256; ++k) s += wfilm[m * 256 + k] * bo[k];
    bf2[m] = s;
  }
}

// ---------------------------------------------------------------------------
// fp32 -> bf16 bulk convert (for folded film weights)
// ---------------------------------------------------------------------------
__global__ __launch_bounds__(256) void cvt_bf16(
    const float* __restrict__ src, short* __restrict__ dst, int n) {
  int i = (blockIdx.x * 256 + threadIdx.x) * 8;
  if (i < n) {
    float4 a = *(const float4*)&src[i];
    float4 c = *(const float4*)&src[i + 4];
    uint4 w;
    w.x = pack2bf(a.x, a.y); w.y = pack2bf(a.z, a.w);
    w.z = pack2bf(c.x, c.y); w.w = pack2bf(c.z, c.w);
    *(uint4*)&dst[i] = w;
  }
}

// ---------------------------------------------------------------------------
// kvprep: K -> rope -> bf16 transposed [bh][s][64ch];  V -> bf16 [bh][64ch][s]
// Grid (TSS/64, NH, NB), block 256. Fast HW trig (revolutions).
// ---------------------------------------------------------------------------
__global__ __launch_bounds__(256) void kvprep(
    const float* __restrict__ kf32, const float* __restrict__ vf32,
    short* __restrict__ kbf, short* __restrict__ vbf) {
  const int s0 = blockIdx.x * 64;
  const int h = blockIdx.y, b = blockIdx.z;
  const int bh = b * NH + h;
  const int tid = threadIdx.x;
  const float* kb = kf32 + ((size_t)(b * CH + h * KC)) * TSS;
  const float* vb = vf32 + ((size_t)(b * CH + h * KC)) * TSS;

  __shared__ float Kls[64 * 68];

  // stage K chunk with fused RoPE (pairs j, j+32)
#pragma unroll
  for (int p = 0; p < 2; ++p) {
    int idx = tid + p * 256;          // 0..511
    int j = idx >> 4, s4 = idx & 15;  // j 0..31
    float4 ka = *(const float4*)&kb[(size_t)j * TSS + s0 + 4 * s4];
    float4 kc = *(const float4*)&kb[(size_t)(j + 32) * TSS + s0 + 4 * s4];
    float invr = __expf(-(float)j * ROPE_C) * INV2PI;
    const float av[4] = {ka.x, ka.y, ka.z, ka.w};
    const float cv[4] = {kc.x, kc.y, kc.z, kc.w};
    float oa[4], oc[4];
#pragma unroll
    for (int e = 0; e < 4; ++e) {
      float sn, cs;
      fast_sincos_rev((float)(s0 + 4 * s4 + e) * invr, &sn, &cs);
      oa[e] = av[e] * cs - cv[e] * sn;
      oc[e] = cv[e] * cs + av[e] * sn;
    }
    *(float4*)&Kls[j * 68 + 4 * s4] = make_float4(oa[0], oa[1], oa[2], oa[3]);
    *(float4*)&Kls[(j + 32) * 68 + 4 * s4] = make_float4(oc[0], oc[1], oc[2], oc[3]);
  }
  __syncthreads();

  // transpose K out: thread -> (s, 16-ch group)
  {
    int s = tid >> 2, g = tid & 3;
    unsigned ow[8];
#pragma unroll
    for (int hlf = 0; hlf < 8; ++hlf) {
      int ch = g * 16 + hlf * 2;
      ow[hlf] = pack2bf(Kls[ch * 68 + s], Kls[(ch + 1) * 68 + s]);
    }
    short* dst = kbf + ((size_t)bh * TSS + s0 + s) * 64 + g * 16;
    *(uint4*)dst = make_uint4(ow[0], ow[1], ow[2], ow[3]);
    *(uint4*)(dst + 8) = make_uint4(ow[4], ow[5], ow[6], ow[7]);
  }

  // V straight cvt
#pragma unroll
  for (int p = 0; p < 4; ++p) {
    int idx = tid + p * 256;          // 0..1023
    int ch = idx >> 4, s4 = idx & 15;
    float4 v = *(const float4*)&vb[(size_t)ch * TSS + s0 + 4 * s4];
    uint2 w2 = make_uint2(pack2bf(v.x, v.y), pack2bf(v.z, v.w));
    *(uint2*)(vbf + ((size_t)bh * KC + ch) * TSS + s0 + 4 * s4) = w2;
  }
}

// ---------------------------------------------------------------------------
// attn_mfma: bf16 MFMA attention — the measured-best r0 structure (86.9 µs)
// with the Q-stage deleted: Q comes pre-roped from q_bf as direct A-frag
// loads. Block = (b, h, 64 t), 4 waves, each owns 16 t. K/V staged in LDS
// per 128-s tile (2 barriers/tile); P (bf16) through per-wave-private LDS
// rows; O written bf16 t-major [b][t][256]. LDS 48 KB -> 3 blocks/CU.
// Layouts (m89/m120-verified): A [m=lane&15][k=quad*8+j]; B same;
// C/D row=quad*4+reg, col=lane&15. All LDS 16B-block XOR-swizzled.
// ---------------------------------------------------------------------------
__global__ __launch_bounds__(256, 3) void attn_mfma(
    const short* __restrict__ qbf, const short* __restrict__ kbf,
    const short* __restrict__ vbf, const float* __restrict__ cond_mask,
    short* __restrict__ obuf) {
  const int t0 = blockIdx.x * 64;
  const int h = blockIdx.y, b = blockIdx.z;
  const int bh = b * NH + h;
  const int tid = threadIdx.x;
  const int w = tid >> 6, lane = tid & 63;
  const int quad = lane >> 4, l15 = lane & 15;

  __shared__ __align__(16) char smem[49152];
  short* Ks = (short*)smem;                 // [s*64 + 8*((ch>>3)^(s&7)) + (ch&7)]   128x64
  short* Vs = (short*)(smem + 16384);       // [ch*128 + 8*((s>>3)^(ch&7)) + (s&7)]  64x128
  short* Ps = (short*)(smem + 32768);       // [t*128 + 8*((s>>3)^(t&7)) + (s&7)]    64x128

  // ---- Q A-frags straight from global (pre-roped bf16) ----
  const short* qb = qbf + ((size_t)bh * TTT + t0) * 64;
  const int trow_l = w * 16 + l15;
  bf16x8 qf0 = *(const bf16x8*)&qb[(size_t)trow_l * 64 + quad * 8];
  bf16x8 qf1 = *(const bf16x8*)&qb[(size_t)trow_l * 64 + 32 + quad * 8];

  f32x4 acc_o[4];
#pragma unroll
  for (int n = 0; n < 4; ++n) acc_o[n] = (f32x4){0.f, 0.f, 0.f, 0.f};
  float den[4] = {0.f, 0.f, 0.f, 0.f};

  const float* cm = cond_mask + (size_t)b * TSS;
  const short* kbase = kbf + (size_t)bh * TSS * 64;
  const short* vbase = vbf + (size_t)bh * KC * TSS;

  for (int s0 = 0; s0 < TSS; s0 += 128) {
    __syncthreads();   // (A) prior tile's K/V frag reads complete
    // ---- stage K, V (bf16, swizzled) ----
#pragma unroll
    for (int p = 0; p < 4; ++p) {
      int idx = tid + p * 256;          // 0..1023
      int blk = idx & 7, sr = idx >> 3; // sr 0..127
      *(uint4*)&Ks[sr * 64 + 8 * (blk ^ (sr & 7))] =
          *(const uint4*)&kbase[(size_t)(s0 + sr) * 64 + 8 * blk];
    }
#pragma unroll
    for (int p = 0; p < 4; ++p) {
      int idx = tid + p * 256;          // 0..1023
      int blk = idx & 15, ch = idx >> 4;
      *(uint4*)&Vs[ch * 128 + 8 * (blk ^ (ch & 7))] =
          *(const uint4*)&vbase[(size_t)ch * TSS + s0 + 8 * blk];
    }
    __syncthreads();   // (B) staging visible

    // ---- QK^T + softmax + P write (P rows are per-wave private) ----
#pragma unroll
    for (int n0 = 0; n0 < 8; ++n0) {
      int srow = n0 * 16 + l15;
      bf16x8 kf0 = *(const bf16x8*)&Ks[srow * 64 + 8 * (quad ^ (srow & 7))];
      bf16x8 kf1 = *(const bf16x8*)&Ks[srow * 64 + 8 * ((4 + quad) ^ (srow & 7))];
      f32x4 acc = (f32x4){0.f, 0.f, 0.f, 0.f};
      acc = __builtin_amdgcn_mfma_f32_16x16x32_bf16(qf0, kf0, acc, 0, 0, 0);
      acc = __builtin_amdgcn_mfma_f32_16x16x32_bf16(qf1, kf1, acc, 0, 0, 0);
      float mk = (cm[s0 + srow] != 0.f) ? 1.f : 0.f;
      int sblk = n0 * 2 + (l15 >> 3);
      int slow = l15 & 7;
#pragma unroll
      for (int r = 0; r < 4; ++r) {
        float e = __expf(acc[r] * 0.125f) * mk;
        den[r] += e;
        int trow = w * 16 + quad * 4 + r;
        Ps[trow * 128 + 8 * (sblk ^ (trow & 7)) + slow] = f2bf(e);
      }
    }

    // ---- PV: O += P V ----
    {
      int trow = w * 16 + l15;
#pragma unroll
      for (int kt = 0; kt < 4; ++kt) {
        bf16x8 pf = *(const bf16x8*)&Ps[trow * 128 + 8 * ((kt * 4 + quad) ^ (trow & 7))];
#pragma unroll
        for (int n0 = 0; n0 < 4; ++n0) {
          int ch = n0 * 16 + l15;
          bf16x8 vf = *(const bf16x8*)&Vs[ch * 128 + 8 * ((kt * 4 + quad) ^ (ch & 7))];
          acc_o[n0] = __builtin_amdgcn_mfma_f32_16x16x32_bf16(pf, vf, acc_o[n0], 0, 0, 0);
        }
      }
    }
  }

  // ---- denominators: reduce over the 16 s-lanes within each quad ----
  float rd[4];
#pragma unroll
  for (int r = 0; r < 4; ++r) {
    float d = den[r];
#pragma unroll
    for (int off = 1; off < 16; off <<= 1) d += __shfl_xor(d, off, 16);
    rd[r] = 1.f / fmaxf(d, 1e-30f);
  }

  // ---- O epilogue: bf16, t-major. Stage [64t][64ch] in LDS, bulk write. ----
  __syncthreads();                 // all PV/K/P reads done; reuse Ks region
  short* Os = (short*)smem;        // [t*64 + ch]  64x64 bf16 (8 KB)
#pragma unroll
  for (int n0 = 0; n0 < 4; ++n0)
#pragma unroll
    for (int r = 0; r < 4; ++r) {
      int ch = n0 * 16 + l15;
      int trow = w * 16 + quad * 4 + r;
      Os[trow * 64 + ch] = f2bf(acc_o[n0][r] * rd[r]);
    }
  __syncthreads();

  short* ob = obuf + ((size_t)b * TTT + t0) * CH + h * KC;
#pragma unroll
  for (int p = 0; p < 2; ++p) {
    int idx = tid + p * 256;         // 0..511 chunks of 8 shorts
    int t = idx >> 3, c8 = idx & 7;
    *(uint4*)&ob[(size_t)t * CH + c8 * 8] = *(const uint4*)&Os[t * 64 + c8 * 8];
  }
}

// ---------------------------------------------------------------------------
// film_mfma: gb = wf2(bf16) @ Ybf(bf16, [b][t][256]) + bf2;
//            out = (x*gamma + beta) * xmask.   (unchanged / passing)
// ---------------------------------------------------------------------------
__global__ __launch_bounds__(256) void film_mfma(
    const short* __restrict__ wfbf, const float* __restrict__ bf2,
    const short* __restrict__ ybf, const float* __restrict__ X,
    const float* __restrict__ xmask, float* __restrict__ out) {
  const int t0 = blockIdx.x * 64;
  const int b = blockIdx.y;
  const int tid = threadIdx.x;
  const int w = tid >> 6, lane = tid & 63;
  const int quad = lane >> 4, l15 = lane & 15;

  __shared__ __align__(16) short Ys[64 * 256];   // [t][ch] bf16, swizzled

  const short* yb = ybf + ((size_t)b * TTT + t0) * CH;
#pragma unroll
  for (int p = 0; p < 8; ++p) {
    int idx = tid + p * 256;          // 0..2047 chunks of 8 shorts
    int cb = idx & 31, tr = idx >> 5; // 32 chunks per row
    *(uint4*)&Ys[tr * 256 + 8 * (cb ^ (tr & 7))] =
        *(const uint4*)&yb[(size_t)tr * CH + 8 * cb];
  }
  __syncthreads();

  const int mbase = w * 64;
  f32x4 accg[4][4], accb[4][4];
#pragma unroll
  for (int mf = 0; mf < 4; ++mf)
#pragma unroll
    for (int nt = 0; nt < 4; ++nt) {
      accg[mf][nt] = (f32x4){0.f, 0.f, 0.f, 0.f};
      accb[mf][nt] = (f32x4){0.f, 0.f, 0.f, 0.f};
    }

#pragma unroll
  for (int k0 = 0; k0 < 256; k0 += 32) {
    const int cb0 = (k0 >> 3) + quad;
    bf16x8 bfr[4];
#pragma unroll
    for (int nt = 0; nt < 4; ++nt) {
      int tr = nt * 16 + l15;
      bfr[nt] = *(const bf16x8*)&Ys[tr * 256 + 8 * (cb0 ^ (tr & 7))];
    }
#pragma unroll
    for (int mf = 0; mf < 4; ++mf) {
      int rowg = mbase + mf * 16 + l15;
      bf16x8 ag = *(const bf16x8*)&wfbf[(size_t)rowg * 256 + k0 + quad * 8];
      bf16x8 ab = *(const bf16x8*)&wfbf[(size_t)(256 + rowg) * 256 + k0 + quad * 8];
#pragma unroll
      for (int nt = 0; nt < 4; ++nt) {
        accg[mf][nt] = __builtin_amdgcn_mfma_f32_16x16x32_bf16(ag, bfr[nt], accg[mf][nt], 0, 0, 0);
        accb[mf][nt] = __builtin_amdgcn_mfma_f32_16x16x32_bf16(ab, bfr[nt], accb[mf][nt], 0, 0, 0);
      }
    }
  }

  const float* xb = X + (size_t)b * CH * TTT + t0;
  const float* xm = xmask + (size_t)b * TTT + t0;
  float* ob = out + (size_t)b * CH * TTT + t0;
  float xmv[4];
#pragma unroll
  for (int nt = 0; nt < 4; ++nt) xmv[nt] = xm[nt * 16 + l15];

#pragma unroll
  for (int mf = 0; mf < 4; ++mf) {
#pragma unroll
    for (int r = 0; r < 4; ++r) {
      int row = mbase + mf * 16 + quad * 4 + r;   // C/D: m = quad*4+reg
      float bg = bf2[row];
      float bb = bf2[256 + row];
#pragma unroll
      for (int nt = 0; nt < 4; ++nt) {
        int t = nt * 16 + l15;                    // C/D: n = lane&15
        float g  = accg[mf][nt][r] + bg;
        float bt = accb[mf][nt][r] + bb;
        float xv = xb[(size_t)row * TTT + t];
        ob[(size_t)row * TTT + t] = (xv * g + bt) * xmv[nt];
      }
    }
  }
}

// ---------------------------------------------------------------------------
extern "C" void kernel_launch(void* const* d_in, const int* in_sizes, int n_in,
                              void* d_out, int out_size, void* d_ws, size_t ws_size,
                              hipStream_t stream) {
  const float* x           = (const float*)d_in[0];
  const float* x_mask      = (const float*)d_in[1];
  const float* cond_latent = (const float*)d_in[2];
  const float* cond_mask   = (const float*)d_in[3];
  const float* w_cond      = (const float*)d_in[4];
  const float* b_cond      = (const float*)d_in[5];
  const float* wq          = (const float*)d_in[6];
  const float* bq          = (const float*)d_in[7];
  const float* wk          = (const float*)d_in[8];
  const float* bk          = (const float*)d_in[9];
  const float* wv          = (const float*)d_in[10];
  const float* bv          = (const float*)d_in[11];
  const float* wo          = (const float*)d_in[12];
  const float* bo          = (const float*)d_in[13];
  const float* w_film      = (const float*)d_in[14];
  const float* b_film      = (const float*)d_in[15];
  float* out = (float*)d_out;

  float* ws = (float*)d_ws;
  float* k_buf = ws;                    // 2,097,152
  float* v_buf = k_buf + 2097152;       // 2,097,152
  float* wk2   = v_buf + 2097152;       // 131,072
  float* wv2   = wk2 + 131072;          // 131,072
  float* wf2   = wv2 + 131072;          // 131,072
  float* bk2   = wf2 + 131072;          // 256
  float* bv2   = bk2 + 256;             // 256
  float* bf2   = bv2 + 256;             // 512
  float* zbuf  = bf2 + 512;             // 512 zeros
  short* k_bf  = (short*)(zbuf + 512);  // 16*4*512*64 bf16
  short* v_bf  = k_bf + 2097152;        // 16*4*64*512 bf16
  short* wf2bf = v_bf + 2097152;        // 512*256 bf16
  short* q_bf  = wf2bf + 131072;        // 16*4*2048*64 bf16 (pre-roped Q frags)
  // attn output (bf16, [b][t][256]) reuses k_buf+v_buf region (free post-kvprep)
  short* o_bf  = (short*)k_buf;         // 16*2048*256 bf16 = 16 MB

  dim3 blk(256);

  hipMemsetAsync(zbuf, 0, 512 * sizeof(float), stream);

  // --- weight folding (tiny GEMMs, B=1) ---
  gemm_v2<4, 2><<<dim3(8, 4, 1), blk, 0, stream>>>(
      wk, zbuf, wv, zbuf, w_cond, wk2, wv2, 256, 512);
  gemm_v2<4, 1><<<dim3(4, 8, 1), blk, 0, stream>>>(
      w_film, zbuf, nullptr, nullptr, wo, wf2, nullptr, 256, 256);
  cvt_bf16<<<dim3(64), blk, 0, stream>>>(wf2, wf2bf, 131072);
  bias_fold<<<dim3(4), blk, 0, stream>>>(wk, bk, wv, bv, b_cond,
                                         w_film, bo, b_film, bk2, bv2, bf2);

  // --- main pipeline ---
  // Q GEMM with fused RoPE + bf16 + transpose epilogue
  gemm_q_rope<<<dim3(16, 4, 16), blk, 0, stream>>>(wq, bq, x, q_bf);
  gemm_v2<4, 2><<<dim3(8, 4, 16), blk, 0, stream>>>(
      wk2, bk2, wv2, bv2, cond_latent, k_buf, v_buf, 512, 512);
  // K rope + transpose + bf16; V bf16
  kvprep<<<dim3(8, 4, 16), blk, 0, stream>>>(k_buf, v_buf, k_bf, v_bf);
  // MFMA attention: r0-structure (64 t/block, staged K/V) + direct Q frags
  attn_mfma<<<dim3(32, 4, 16), blk, 0, stream>>>(q_bf, k_bf, v_bf, cond_mask, o_bf);
  // MFMA film + final output
  film_mfma<<<dim3(32, 16), blk, 0, stream>>>(wf2bf, bf2, o_bf, x, x_mask, out);
}

// Round 6
// 339.526 us; speedup vs baseline: 1.4826x; 1.0896x over previous
//
#include <hip/hip_runtime.h>
#include <math.h>

#define NB 16        // batch
#define CH 256       // hidden
#define NH 4
#define KC 64
#define TTT 2048
#define TSS 512

typedef __attribute__((ext_vector_type(8))) short bf16x8;
typedef __attribute__((ext_vector_type(4))) float f32x4;

__device__ inline short f2bf(float x) {   // round-to-nearest-even bf16
  unsigned u = __float_as_uint(x);
  u += 0x7fffu + ((u >> 16) & 1u);
  return (short)(u >> 16);
}
__device__ inline unsigned pack2bf(float a, float b) {
  return (unsigned)(unsigned short)f2bf(a) | ((unsigned)(unsigned short)f2bf(b) << 16);
}

// fast sincos, input in revolutions (fract-reduced to [0,1), inside HW range)
__device__ inline void fast_sincos_rev(float rev, float* sn, float* cs) {
  float fr = rev - truncf(rev);
#if __has_builtin(__builtin_amdgcn_sinf)
  *sn = __builtin_amdgcn_sinf(fr);
  *cs = __builtin_amdgcn_cosf(fr);
#else
  float ang = fr * 6.28318530717958648f;
  *sn = __sinf(ang);
  *cs = __cosf(ang);
#endif
}

#define INV2PI 0.15915494309189535f
#define ROPE_C 0.28782313662425572f   // ln(10000)*2/64

// ---------------------------------------------------------------------------
// Templated tiled GEMM: Yn[b] = Wn @ X[b] + bn  (fp32; folds only now)
// ---------------------------------------------------------------------------
template <int TN, int NOUT>
__global__ __launch_bounds__(256) void gemm_v2(
    const float* __restrict__ W0, const float* __restrict__ b0,
    const float* __restrict__ W1, const float* __restrict__ b1,
    const float* __restrict__ X, float* __restrict__ Y0, float* __restrict__ Y1,
    int K, int T) {
  constexpr int TT = 16 * TN;
  constexpr int TQ = TT / 4;
  constexpr int PB = (32 * TQ) / 256;
  const int t0 = blockIdx.x * TT;
  const int m0 = blockIdx.y * 64;
  const int b  = blockIdx.z;
  const int tid = threadIdx.x;
  const int tx = tid & 15, ty = tid >> 4;

  __shared__ float As[NOUT][32][68];
  __shared__ float Bs[32][TT + 4];

  const float* Xb = X + (size_t)b * K * T;
  float acc[NOUT][4][TN];
#pragma unroll
  for (int n = 0; n < NOUT; ++n)
#pragma unroll
    for (int i = 0; i < 4; ++i)
#pragma unroll
      for (int u = 0; u < TN; ++u) acc[n][i][u] = 0.f;

  const int am = tid >> 2, akq = tid & 3;

  for (int k0 = 0; k0 < K; k0 += 32) {
#pragma unroll
    for (int n = 0; n < NOUT; ++n) {
      const float* Wn = (n == 0) ? W0 : W1;
      float4 a0 = *(const float4*)&Wn[(size_t)(m0 + am) * K + k0 + 4 * akq];
      float4 a1 = *(const float4*)&Wn[(size_t)(m0 + am) * K + k0 + 16 + 4 * akq];
      As[n][4 * akq + 0][am] = a0.x; As[n][4 * akq + 1][am] = a0.y;
      As[n][4 * akq + 2][am] = a0.z; As[n][4 * akq + 3][am] = a0.w;
      As[n][16 + 4 * akq + 0][am] = a1.x; As[n][16 + 4 * akq + 1][am] = a1.y;
      As[n][16 + 4 * akq + 2][am] = a1.z; As[n][16 + 4 * akq + 3][am] = a1.w;
    }
#pragma unroll
    for (int p = 0; p < PB; ++p) {
      int idx = tid + p * 256;
      int t4 = idx & (TQ - 1), k = idx / TQ;
      *(float4*)&Bs[k][4 * t4] = *(const float4*)&Xb[(size_t)(k0 + k) * T + t0 + 4 * t4];
    }
    __syncthreads();
#pragma unroll
    for (int kk = 0; kk < 32; ++kk) {
      float4 av[NOUT];
#pragma unroll
      for (int n = 0; n < NOUT; ++n) av[n] = *(const float4*)&As[n][kk][4 * ty];
      float4 bv[TN / 4];
#pragma unroll
      for (int g = 0; g < TN / 4; ++g) bv[g] = *(const float4*)&Bs[kk][4 * tx + 64 * g];
#pragma unroll
      for (int n = 0; n < NOUT; ++n) {
        const float a4[4] = {av[n].x, av[n].y, av[n].z, av[n].w};
#pragma unroll
        for (int i = 0; i < 4; ++i)
#pragma unroll
          for (int g = 0; g < TN / 4; ++g) {
            acc[n][i][4 * g + 0] += a4[i] * bv[g].x;
            acc[n][i][4 * g + 1] += a4[i] * bv[g].y;
            acc[n][i][4 * g + 2] += a4[i] * bv[g].z;
            acc[n][i][4 * g + 3] += a4[i] * bv[g].w;
          }
      }
    }
    __syncthreads();
  }
#pragma unroll
  for (int n = 0; n < NOUT; ++n) {
    float* Yn = (n == 0) ? Y0 : Y1;
    const float* bn = (n == 0) ? b0 : b1;
#pragma unroll
    for (int i = 0; i < 4; ++i) {
      int row = m0 + 4 * ty + i;
      float bi = bn[row];
#pragma unroll
      for (int g = 0; g < TN / 4; ++g) {
        float4 ov;
        ov.x = acc[n][i][4 * g + 0] + bi; ov.y = acc[n][i][4 * g + 1] + bi;
        ov.z = acc[n][i][4 * g + 2] + bi; ov.w = acc[n][i][4 * g + 3] + bi;
        *(float4*)&Yn[((size_t)b * 256 + row) * T + t0 + 4 * tx + 64 * g] = ov;
      }
    }
  }
}

// ---------------------------------------------------------------------------
// gemm_q_mfma: Q = Wq(bf16) @ x(bf16-staged) + bq, fused RoPE, out bf16
// A-frags [bh][t][64]. Block = (64 t, b), 4 waves, wave w = head w (64 m-rows).
// x tile staged fp32 in LDS with col-XOR ((k>>3)&3)*16 (<=2-way banks on
// per-quad strided frag reads). C/D (row=quad*4+r, col=l15) -> Ep[256][71]
// (stride 71: cb-phase reads conflict-free), then the verified rope+transpose
// epilogue (sincos shared across heads). LDS 72.7 KB -> 2 blocks/CU (grid 512).
// ---------------------------------------------------------------------------
__global__ __launch_bounds__(256, 2) void gemm_q_mfma(
    const short* __restrict__ wqbf, const float* __restrict__ bq,
    const float* __restrict__ X, short* __restrict__ qbf) {
  const int t0 = blockIdx.x * 64;
  const int b  = blockIdx.y;
  const int tid = threadIdx.x;
  const int w = tid >> 6, lane = tid & 63;
  const int quad = lane >> 4, l15 = lane & 15;

  __shared__ __align__(16) char smem[72704];
  float* Bsq = (float*)smem;          // [256k][68t] f32, col-XOR-swizzled
  float* Ep  = (float*)smem;          // [256row][71t] f32 (aliased post-loop)

  // ---- stage x tile [256ch][64t] fp32, col-swizzled ----
  const float* xb = X + (size_t)b * CH * TTT + t0;
#pragma unroll
  for (int p = 0; p < 16; ++p) {
    int idx = tid + p * 256;
    int t4 = idx & 15, k = idx >> 4;
    int swz = ((k >> 3) & 3) * 16;
    *(float4*)&Bsq[k * 68 + ((4 * t4) ^ swz)] =
        *(const float4*)&xb[(size_t)k * TTT + 4 * t4];
  }
  __syncthreads();

  const int mbase = w * 64;
  f32x4 acc[4][4];
#pragma unroll
  for (int mf = 0; mf < 4; ++mf)
#pragma unroll
    for (int nt = 0; nt < 4; ++nt) acc[mf][nt] = (f32x4){0.f, 0.f, 0.f, 0.f};

#pragma unroll
  for (int k0 = 0; k0 < 256; k0 += 32) {
    bf16x8 bfr[4];
#pragma unroll
    for (int nt = 0; nt < 4; ++nt) {
      int col = (nt * 16 + l15) ^ (quad * 16);
      bf16x8 f;
#pragma unroll
      for (int j = 0; j < 8; ++j)
        f[j] = f2bf(Bsq[(k0 + quad * 8 + j) * 68 + col]);
      bfr[nt] = f;
    }
#pragma unroll
    for (int mf = 0; mf < 4; ++mf) {
      bf16x8 af = *(const bf16x8*)&wqbf[(size_t)(mbase + mf * 16 + l15) * 256 + k0 + quad * 8];
#pragma unroll
      for (int nt = 0; nt < 4; ++nt)
        acc[mf][nt] = __builtin_amdgcn_mfma_f32_16x16x32_bf16(af, bfr[nt], acc[mf][nt], 0, 0, 0);
    }
  }
  __syncthreads();   // all Bsq reads complete; alias as Ep

  // ---- acc (+bias) -> Ep [256][71] ----
#pragma unroll
  for (int mf = 0; mf < 4; ++mf)
#pragma unroll
    for (int r = 0; r < 4; ++r) {
      int row = mbase + mf * 16 + quad * 4 + r;
      float bi = bq[row];
#pragma unroll
      for (int nt = 0; nt < 4; ++nt)
        Ep[row * 71 + nt * 16 + l15] = acc[mf][nt][r] + bi;
    }
  __syncthreads();

  // ---- rope + bf16 + transposed write (loop all 4 heads) ----
  const int tt = tid >> 2, cb = tid & 3;
  float sn[8], cs[8];
  const float tg = (float)(t0 + tt);
#pragma unroll
  for (int e = 0; e < 8; ++e) {
    float invr = __expf(-(float)(cb * 8 + e) * ROPE_C) * INV2PI;
    fast_sincos_rev(tg * invr, &sn[e], &cs[e]);
  }
#pragma unroll
  for (int hh = 0; hh < 4; ++hh) {
    float oa[8], oc[8];
#pragma unroll
    for (int e = 0; e < 8; ++e) {
      int j = cb * 8 + e;
      float a = Ep[(hh * 64 + j) * 71 + tt];
      float c = Ep[(hh * 64 + j + 32) * 71 + tt];
      oa[e] = a * cs[e] - c * sn[e];
      oc[e] = c * cs[e] + a * sn[e];
    }
    short* dst = qbf + ((size_t)(b * NH + hh) * TTT + t0 + tt) * 64 + cb * 8;
    *(uint4*)dst = make_uint4(pack2bf(oa[0], oa[1]), pack2bf(oa[2], oa[3]),
                              pack2bf(oa[4], oa[5]), pack2bf(oa[6], oa[7]));
    *(uint4*)(dst + 32) = make_uint4(pack2bf(oc[0], oc[1]), pack2bf(oc[2], oc[3]),
                                     pack2bf(oc[4], oc[5]), pack2bf(oc[6], oc[7]));
  }
}

// ---------------------------------------------------------------------------
// gemm_kv_rope: fp32 GEMM core (identical numerics to gemm_v2<4,2>) with
// fused epilogues: V -> bf16 [bh][ch][s] direct; K -> (+bias) LDS stage
// [64][71] then kvprep's rope+transpose -> bf16 [bh][s][64]. kvprep deleted.
// Grid (8 s-tiles, NH, NB), block 256.
// ---------------------------------------------------------------------------
__global__ __launch_bounds__(256) void gemm_kv_rope(
    const float* __restrict__ W0, const float* __restrict__ b0,
    const float* __restrict__ W1, const float* __restrict__ b1,
    const float* __restrict__ X, short* __restrict__ kbf, short* __restrict__ vbf) {
  const int t0 = blockIdx.x * 64;   // s-tile base
  const int by = blockIdx.y;        // head
  const int b  = blockIdx.z;
  const int m0 = by * 64;
  const int tid = threadIdx.x;
  const int tx = tid & 15, ty = tid >> 4;
  const int K = 512, T = 512;

  __shared__ __align__(16) char ksm[26112];
  float* As = (float*)ksm;             // [2][32][68] = 17408 B
  float* Bs = (float*)(ksm + 17408);   // [32][68]    =  8704 B
  float* Kls = (float*)ksm;            // [64][71] epilogue alias (18176 B)

  const float* Xb = X + (size_t)b * K * T;
  float acc[2][4][4];
#pragma unroll
  for (int n = 0; n < 2; ++n)
#pragma unroll
    for (int i = 0; i < 4; ++i)
#pragma unroll
      for (int u = 0; u < 4; ++u) acc[n][i][u] = 0.f;

  const int am = tid >> 2, akq = tid & 3;

  for (int k0 = 0; k0 < K; k0 += 32) {
#pragma unroll
    for (int n = 0; n < 2; ++n) {
      const float* Wn = (n == 0) ? W0 : W1;
      float4 a0 = *(const float4*)&Wn[(size_t)(m0 + am) * K + k0 + 4 * akq];
      float4 a1 = *(const float4*)&Wn[(size_t)(m0 + am) * K + k0 + 16 + 4 * akq];
      float* An = As + n * 32 * 68;
      An[(4 * akq + 0) * 68 + am] = a0.x; An[(4 * akq + 1) * 68 + am] = a0.y;
      An[(4 * akq + 2) * 68 + am] = a0.z; An[(4 * akq + 3) * 68 + am] = a0.w;
      An[(16 + 4 * akq + 0) * 68 + am] = a1.x; An[(16 + 4 * akq + 1) * 68 + am] = a1.y;
      An[(16 + 4 * akq + 2) * 68 + am] = a1.z; An[(16 + 4 * akq + 3) * 68 + am] = a1.w;
    }
#pragma unroll
    for (int p = 0; p < 2; ++p) {
      int idx = tid + p * 256;
      int t4 = idx & 15, k = idx >> 4;
      *(float4*)&Bs[k * 68 + 4 * t4] = *(const float4*)&Xb[(size_t)(k0 + k) * T + t0 + 4 * t4];
    }
    __syncthreads();
#pragma unroll
    for (int kk = 0; kk < 32; ++kk) {
      float4 av0 = *(const float4*)&As[kk * 68 + 4 * ty];
      float4 av1 = *(const float4*)&As[32 * 68 + kk * 68 + 4 * ty];
      float4 bv = *(const float4*)&Bs[kk * 68 + 4 * tx];
      const float a0[4] = {av0.x, av0.y, av0.z, av0.w};
      const float a1[4] = {av1.x, av1.y, av1.z, av1.w};
#pragma unroll
      for (int i = 0; i < 4; ++i) {
        acc[0][i][0] += a0[i] * bv.x; acc[0][i][1] += a0[i] * bv.y;
        acc[0][i][2] += a0[i] * bv.z; acc[0][i][3] += a0[i] * bv.w;
        acc[1][i][0] += a1[i] * bv.x; acc[1][i][1] += a1[i] * bv.y;
        acc[1][i][2] += a1[i] * bv.z; acc[1][i][3] += a1[i] * bv.w;
      }
    }
    __syncthreads();
  }

  const int bh = b * NH + by;

  // ---- V: direct bf16 write [bh][ch][s] ----
#pragma unroll
  for (int i = 0; i < 4; ++i) {
    int row = m0 + 4 * ty + i;
    float bvv = b1[row];
    uint2 w2 = make_uint2(pack2bf(acc[1][i][0] + bvv, acc[1][i][1] + bvv),
                          pack2bf(acc[1][i][2] + bvv, acc[1][i][3] + bvv));
    *(uint2*)&vbf[((size_t)bh * KC + (row & 63)) * TSS + t0 + 4 * tx] = w2;
  }

  // ---- K: stage fp32 (+bias) into Kls [64ch][71s] (aliases As/Bs) ----
#pragma unroll
  for (int i = 0; i < 4; ++i) {
    int row = m0 + 4 * ty + i;
    float bkk = b0[row];
#pragma unroll
    for (int u = 0; u < 4; ++u)
      Kls[(4 * ty + i) * 71 + 4 * tx + u] = acc[0][i][u] + bkk;
  }
  __syncthreads();

  // ---- rope + transpose out: thread -> (s, 16-ch group) ----
  {
    int s = tid >> 2, g = tid & 3;
    float sg = (float)(t0 + s);
    unsigned ow[8];
#pragma unroll
    for (int hlf = 0; hlf < 8; ++hlf) {
      int ch = g * 16 + hlf * 2;
      float o2[2];
#pragma unroll
      for (int q = 0; q < 2; ++q) {
        int c = ch + q;
        int j = c & 31;
        float invr = __expf(-(float)j * ROPE_C) * INV2PI;
        float snv, csv;
        fast_sincos_rev(sg * invr, &snv, &csv);
        float a = Kls[c * 71 + s];
        float p = Kls[(c ^ 32) * 71 + s];
        o2[q] = (c < 32) ? (a * csv - p * snv) : (a * csv + p * snv);
      }
      ow[hlf] = pack2bf(o2[0], o2[1]);
    }
    short* dst = kbf + ((size_t)bh * TSS + t0 + s) * 64 + g * 16;
    *(uint4*)dst = make_uint4(ow[0], ow[1], ow[2], ow[3]);
    *(uint4*)(dst + 8) = make_uint4(ow[4], ow[5], ow[6], ow[7]);
  }
}

// ---------------------------------------------------------------------------
// Bias folding (unchanged / passing)
// ---------------------------------------------------------------------------
__global__ __launch_bounds__(256) void bias_fold(
    const float* __restrict__ wk, const float* __restrict__ bk,
    const float* __restrict__ wv, const float* __restrict__ bv,
    const float* __restrict__ bcond,
    const float* __restrict__ wfilm, const float* __restrict__ bo,
    const float* __restrict__ bfilm,
    float* __restrict__ bk2, float* __restrict__ bv2, float* __restrict__ bf2) {
  int g = blockIdx.x * 256 + threadIdx.x;
  if (g < 256) {
    float s = bk[g];
    for (int k = 0; k < 256; ++k) s += wk[g * 256 + k] * bcond[k];
    bk2[g] = s;
  } else if (g < 512) {
    int m = g - 256;
    float s = bv[m];
    for (int k = 0; k < 256; ++k) s += wv[m * 256 + k] * bcond[k];
    bv2[m] = s;
  } else if (g < 1024) {
    int m = g - 512;
    float s = bfilm[m];
    for (int k = 0; k < 256; ++k) s += wfilm[m * 256 + k] * bo[k];
    bf2[m] = s;
  }
}

// ---------------------------------------------------------------------------
// fp32 -> bf16 bulk convert
// ---------------------------------------------------------------------------
__global__ __launch_bounds__(256) void cvt_bf16(
    const float* __restrict__ src, short* __restrict__ dst, int n) {
  int i = (blockIdx.x * 256 + threadIdx.x) * 8;
  if (i < n) {
    float4 a = *(const float4*)&src[i];
    float4 c = *(const float4*)&src[i + 4];
    uint4 w;
    w.x = pack2bf(a.x, a.y); w.y = pack2bf(a.z, a.w);
    w.z = pack2bf(c.x, c.y); w.w = pack2bf(c.z, c.w);
    *(uint4*)&dst[i] = w;
  }
}

// ---------------------------------------------------------------------------
// attn_mfma: r0 structure + direct pre-roped Q frags (measured 77 µs).
// Block = (b, h, 64 t), 4 waves. K/V staged per 128-s tile (2 barriers);
// P via per-wave-private LDS; O bf16 t-major. LDS 48 KB -> 3 blocks/CU.
// ---------------------------------------------------------------------------
__global__ __launch_bounds__(256, 3) void attn_mfma(
    const short* __restrict__ qbf, const short* __restrict__ kbf,
    const short* __restrict__ vbf, const float* __restrict__ cond_mask,
    short* __restrict__ obuf) {
  const int t0 = blockIdx.x * 64;
  const int h = blockIdx.y, b = blockIdx.z;
  const int bh = b * NH + h;
  const int tid = threadIdx.x;
  const int w = tid >> 6, lane = tid & 63;
  const int quad = lane >> 4, l15 = lane & 15;

  __shared__ __align__(16) char smem[49152];
  short* Ks = (short*)smem;                 // 128x64 swizzled
  short* Vs = (short*)(smem + 16384);       // 64x128 swizzled
  short* Ps = (short*)(smem + 32768);       // 64x128 swizzled

  const short* qb = qbf + ((size_t)bh * TTT + t0) * 64;
  const int trow_l = w * 16 + l15;
  bf16x8 qf0 = *(const bf16x8*)&qb[(size_t)trow_l * 64 + quad * 8];
  bf16x8 qf1 = *(const bf16x8*)&qb[(size_t)trow_l * 64 + 32 + quad * 8];

  f32x4 acc_o[4];
#pragma unroll
  for (int n = 0; n < 4; ++n) acc_o[n] = (f32x4){0.f, 0.f, 0.f, 0.f};
  float den[4] = {0.f, 0.f, 0.f, 0.f};

  const float* cm = cond_mask + (size_t)b * TSS;
  const short* kbase = kbf + (size_t)bh * TSS * 64;
  const short* vbase = vbf + (size_t)bh * KC * TSS;

  for (int s0 = 0; s0 < TSS; s0 += 128) {
    __syncthreads();
#pragma unroll
    for (int p = 0; p < 4; ++p) {
      int idx = tid + p * 256;
      int blk = idx & 7, sr = idx >> 3;
      *(uint4*)&Ks[sr * 64 + 8 * (blk ^ (sr & 7))] =
          *(const uint4*)&kbase[(size_t)(s0 + sr) * 64 + 8 * blk];
    }
#pragma unroll
    for (int p = 0; p < 4; ++p) {
      int idx = tid + p * 256;
      int blk = idx & 15, ch = idx >> 4;
      *(uint4*)&Vs[ch * 128 + 8 * (blk ^ (ch & 7))] =
          *(const uint4*)&vbase[(size_t)ch * TSS + s0 + 8 * blk];
    }
    __syncthreads();

#pragma unroll
    for (int n0 = 0; n0 < 8; ++n0) {
      int srow = n0 * 16 + l15;
      bf16x8 kf0 = *(const bf16x8*)&Ks[srow * 64 + 8 * (quad ^ (srow & 7))];
      bf16x8 kf1 = *(const bf16x8*)&Ks[srow * 64 + 8 * ((4 + quad) ^ (srow & 7))];
      f32x4 acc = (f32x4){0.f, 0.f, 0.f, 0.f};
      acc = __builtin_amdgcn_mfma_f32_16x16x32_bf16(qf0, kf0, acc, 0, 0, 0);
      acc = __builtin_amdgcn_mfma_f32_16x16x32_bf16(qf1, kf1, acc, 0, 0, 0);
      float mk = (cm[s0 + srow] != 0.f) ? 1.f : 0.f;
      int sblk = n0 * 2 + (l15 >> 3);
      int slow = l15 & 7;
#pragma unroll
      for (int r = 0; r < 4; ++r) {
        float e = __expf(acc[r] * 0.125f) * mk;
        den[r] += e;
        int trow = w * 16 + quad * 4 + r;
        Ps[trow * 128 + 8 * (sblk ^ (trow & 7)) + slow] = f2bf(e);
      }
    }

    {
      int trow = w * 16 + l15;
#pragma unroll
      for (int kt = 0; kt < 4; ++kt) {
        bf16x8 pf = *(const bf16x8*)&Ps[trow * 128 + 8 * ((kt * 4 + quad) ^ (trow & 7))];
#pragma unroll
        for (int n0 = 0; n0 < 4; ++n0) {
          int ch = n0 * 16 + l15;
          bf16x8 vf = *(const bf16x8*)&Vs[ch * 128 + 8 * ((kt * 4 + quad) ^ (ch & 7))];
          acc_o[n0] = __builtin_amdgcn_mfma_f32_16x16x32_bf16(pf, vf, acc_o[n0], 0, 0, 0);
        }
      }
    }
  }

  float rd[4];
#pragma unroll
  for (int r = 0; r < 4; ++r) {
    float d = den[r];
#pragma unroll
    for (int off = 1; off < 16; off <<= 1) d += __shfl_xor(d, off, 16);
    rd[r] = 1.f / fmaxf(d, 1e-30f);
  }

  __syncthreads();
  short* Os = (short*)smem;
#pragma unroll
  for (int n0 = 0; n0 < 4; ++n0)
#pragma unroll
    for (int r = 0; r < 4; ++r) {
      int ch = n0 * 16 + l15;
      int trow = w * 16 + quad * 4 + r;
      Os[trow * 64 + ch] = f2bf(acc_o[n0][r] * rd[r]);
    }
  __syncthreads();

  short* ob = obuf + ((size_t)b * TTT + t0) * CH + h * KC;
#pragma unroll
  for (int p = 0; p < 2; ++p) {
    int idx = tid + p * 256;
    int t = idx >> 3, c8 = idx & 7;
    *(uint4*)&ob[(size_t)t * CH + c8 * 8] = *(const uint4*)&Os[t * 64 + c8 * 8];
  }
}

// ---------------------------------------------------------------------------
// film_mfma (unchanged / passing)
// ---------------------------------------------------------------------------
__global__ __launch_bounds__(256) void film_mfma(
    const short* __restrict__ wfbf, const float* __restrict__ bf2,
    const short* __restrict__ ybf, const float* __restrict__ X,
    const float* __restrict__ xmask, float* __restrict__ out) {
  const int t0 = blockIdx.x * 64;
  const int b = blockIdx.y;
  const int tid = threadIdx.x;
  const int w = tid >> 6, lane = tid & 63;
  const int quad = lane >> 4, l15 = lane & 15;

  __shared__ __align__(16) short Ys[64 * 256];

  const short* yb = ybf + ((size_t)b * TTT + t0) * CH;
#pragma unroll
  for (int p = 0; p < 8; ++p) {
    int idx = tid + p * 256;
    int cb = idx & 31, tr = idx >> 5;
    *(uint4*)&Ys[tr * 256 + 8 * (cb ^ (tr & 7))] =
        *(const uint4*)&yb[(size_t)tr * CH + 8 * cb];
  }
  __syncthreads();

  const int mbase = w * 64;
  f32x4 accg[4][4], accb[4][4];
#pragma unroll
  for (int mf = 0; mf < 4; ++mf)
#pragma unroll
    for (int nt = 0; nt < 4; ++nt) {
      accg[mf][nt] = (f32x4){0.f, 0.f, 0.f, 0.f};
      accb[mf][nt] = (f32x4){0.f, 0.f, 0.f, 0.f};
    }

#pragma unroll
  for (int k0 = 0; k0 < 256; k0 += 32) {
    const int cb0 = (k0 >> 3) + quad;
    bf16x8 bfr[4];
#pragma unroll
    for (int nt = 0; nt < 4; ++nt) {
      int tr = nt * 16 + l15;
      bfr[nt] = *(const bf16x8*)&Ys[tr * 256 + 8 * (cb0 ^ (tr & 7))];
    }
#pragma unroll
    for (int mf = 0; mf < 4; ++mf) {
      int rowg = mbase + mf * 16 + l15;
      bf16x8 ag = *(const bf16x8*)&wfbf[(size_t)rowg * 256 + k0 + quad * 8];
      bf16x8 ab = *(const bf16x8*)&wfbf[(size_t)(256 + rowg) * 256 + k0 + quad * 8];
#pragma unroll
      for (int nt = 0; nt < 4; ++nt) {
        accg[mf][nt] = __builtin_amdgcn_mfma_f32_16x16x32_bf16(ag, bfr[nt], accg[mf][nt], 0, 0, 0);
        accb[mf][nt] = __builtin_amdgcn_mfma_f32_16x16x32_bf16(ab, bfr[nt], accb[mf][nt], 0, 0, 0);
      }
    }
  }

  const float* xb = X + (size_t)b * CH * TTT + t0;
  const float* xm = xmask + (size_t)b * TTT + t0;
  float* ob = out + (size_t)b * CH * TTT + t0;
  float xmv[4];
#pragma unroll
  for (int nt = 0; nt < 4; ++nt) xmv[nt] = xm[nt * 16 + l15];

#pragma unroll
  for (int mf = 0; mf < 4; ++mf) {
#pragma unroll
    for (int r = 0; r < 4; ++r) {
      int row = mbase + mf * 16 + quad * 4 + r;
      float bg = bf2[row];
      float bb = bf2[256 + row];
#pragma unroll
      for (int nt = 0; nt < 4; ++nt) {
        int t = nt * 16 + l15;
        float g  = accg[mf][nt][r] + bg;
        float bt = accb[mf][nt][r] + bb;
        float xv = xb[(size_t)row * TTT + t];
        ob[(size_t)row * TTT + t] = (xv * g + bt) * xmv[nt];
      }
    }
  }
}

// ---------------------------------------------------------------------------
extern "C" void kernel_launch(void* const* d_in, const int* in_sizes, int n_in,
                              void* d_out, int out_size, void* d_ws, size_t ws_size,
                              hipStream_t stream) {
  const float* x           = (const float*)d_in[0];
  const float* x_mask      = (const float*)d_in[1];
  const float* cond_latent = (const float*)d_in[2];
  const float* cond_mask   = (const float*)d_in[3];
  const float* w_cond      = (const float*)d_in[4];
  const float* b_cond      = (const float*)d_in[5];
  const float* wq          = (const float*)d_in[6];
  const float* bq          = (const float*)d_in[7];
  const float* wk          = (const float*)d_in[8];
  const float* bk          = (const float*)d_in[9];
  const float* wv          = (const float*)d_in[10];
  const float* bv          = (const float*)d_in[11];
  const float* wo          = (const float*)d_in[12];
  const float* bo          = (const float*)d_in[13];
  const float* w_film      = (const float*)d_in[14];
  const float* b_film      = (const float*)d_in[15];
  float* out = (float*)d_out;

  float* ws = (float*)d_ws;
  float* k_buf = ws;                    // (region reused by o_bf)
  float* v_buf = k_buf + 2097152;
  float* wk2   = v_buf + 2097152;       // 131,072
  float* wv2   = wk2 + 131072;          // 131,072
  float* wf2   = wv2 + 131072;          // 131,072
  float* bk2   = wf2 + 131072;          // 256
  float* bv2   = bk2 + 256;             // 256
  float* bf2   = bv2 + 256;             // 512
  float* zbuf  = bf2 + 512;             // 512 zeros
  short* k_bf  = (short*)(zbuf + 512);  // 16*4*512*64 bf16
  short* v_bf  = k_bf + 2097152;        // 16*4*64*512 bf16
  short* wf2bf = v_bf + 2097152;        // 512*256 bf16
  short* q_bf  = wf2bf + 131072;        // 16*4*2048*64 bf16
  short* wq_bf = q_bf + 8388608;        // 256*256 bf16
  short* o_bf  = (short*)k_buf;         // 16*2048*256 bf16 (aliases k/v_buf)

  dim3 blk(256);

  hipMemsetAsync(zbuf, 0, 512 * sizeof(float), stream);

  // --- weight folding + casts ---
  cvt_bf16<<<dim3(32), blk, 0, stream>>>(wq, wq_bf, 65536);
  gemm_v2<4, 2><<<dim3(8, 4, 1), blk, 0, stream>>>(
      wk, zbuf, wv, zbuf, w_cond, wk2, wv2, 256, 512);
  gemm_v2<4, 1><<<dim3(4, 8, 1), blk, 0, stream>>>(
      w_film, zbuf, nullptr, nullptr, wo, wf2, nullptr, 256, 256);
  cvt_bf16<<<dim3(64), blk, 0, stream>>>(wf2, wf2bf, 131072);
  bias_fold<<<dim3(4), blk, 0, stream>>>(wk, bk, wv, bv, b_cond,
                                         w_film, bo, b_film, bk2, bv2, bf2);

  // --- main pipeline ---
  // Q projection on MFMA with fused RoPE + bf16 + transpose
  gemm_q_mfma<<<dim3(32, 16), blk, 0, stream>>>(wq_bf, bq, x, q_bf);
  // K/V projection (fp32 core) with fused rope/bf16 epilogues (kvprep gone)
  gemm_kv_rope<<<dim3(8, 4, 16), blk, 0, stream>>>(
      wk2, bk2, wv2, bv2, cond_latent, k_bf, v_bf);
  // MFMA attention (r0 structure, 64 t/block)
  attn_mfma<<<dim3(32, 4, 16), blk, 0, stream>>>(q_bf, k_bf, v_bf, cond_mask, o_bf);
  // MFMA film + final output
  film_mfma<<<dim3(32, 16), blk, 0, stream>>>(wf2bf, bf2, o_bf, x, x_mask, out);
}

// Round 7
// 293.760 us; speedup vs baseline: 1.7136x; 1.1558x over previous
//
#include <hip/hip_runtime.h>
#include <math.h>

#define NB 16        // batch
#define CH 256       // hidden
#define NH 4
#define KC 64
#define TTT 2048
#define TSS 512

typedef __attribute__((ext_vector_type(8))) short bf16x8;
typedef __attribute__((ext_vector_type(4))) float f32x4;

__device__ inline short f2bf(float x) {   // round-to-nearest-even bf16
  unsigned u = __float_as_uint(x);
  u += 0x7fffu + ((u >> 16) & 1u);
  return (short)(u >> 16);
}
__device__ inline unsigned pack2bf(float a, float b) {
  return (unsigned)(unsigned short)f2bf(a) | ((unsigned)(unsigned short)f2bf(b) << 16);
}

// fast sincos, input in revolutions (fract-reduced to [0,1), inside HW range)
__device__ inline void fast_sincos_rev(float rev, float* sn, float* cs) {
  float fr = rev - truncf(rev);
#if __has_builtin(__builtin_amdgcn_sinf)
  *sn = __builtin_amdgcn_sinf(fr);
  *cs = __builtin_amdgcn_cosf(fr);
#else
  float ang = fr * 6.28318530717958648f;
  *sn = __sinf(ang);
  *cs = __cosf(ang);
#endif
}

#define INV2PI 0.15915494309189535f
#define ROPE_C 0.28782313662425572f   // ln(10000)*2/64

// ---------------------------------------------------------------------------
// Templated tiled GEMM: Yn[b] = Wn @ X[b] + bn  (fp32; weight folds only)
// ---------------------------------------------------------------------------
template <int TN, int NOUT>
__global__ __launch_bounds__(256) void gemm_v2(
    const float* __restrict__ W0, const float* __restrict__ b0,
    const float* __restrict__ W1, const float* __restrict__ b1,
    const float* __restrict__ X, float* __restrict__ Y0, float* __restrict__ Y1,
    int K, int T) {
  constexpr int TT = 16 * TN;
  constexpr int TQ = TT / 4;
  constexpr int PB = (32 * TQ) / 256;
  const int t0 = blockIdx.x * TT;
  const int m0 = blockIdx.y * 64;
  const int b  = blockIdx.z;
  const int tid = threadIdx.x;
  const int tx = tid & 15, ty = tid >> 4;

  __shared__ float As[NOUT][32][68];
  __shared__ float Bs[32][TT + 4];

  const float* Xb = X + (size_t)b * K * T;
  float acc[NOUT][4][TN];
#pragma unroll
  for (int n = 0; n < NOUT; ++n)
#pragma unroll
    for (int i = 0; i < 4; ++i)
#pragma unroll
      for (int u = 0; u < TN; ++u) acc[n][i][u] = 0.f;

  const int am = tid >> 2, akq = tid & 3;

  for (int k0 = 0; k0 < K; k0 += 32) {
#pragma unroll
    for (int n = 0; n < NOUT; ++n) {
      const float* Wn = (n == 0) ? W0 : W1;
      float4 a0 = *(const float4*)&Wn[(size_t)(m0 + am) * K + k0 + 4 * akq];
      float4 a1 = *(const float4*)&Wn[(size_t)(m0 + am) * K + k0 + 16 + 4 * akq];
      As[n][4 * akq + 0][am] = a0.x; As[n][4 * akq + 1][am] = a0.y;
      As[n][4 * akq + 2][am] = a0.z; As[n][4 * akq + 3][am] = a0.w;
      As[n][16 + 4 * akq + 0][am] = a1.x; As[n][16 + 4 * akq + 1][am] = a1.y;
      As[n][16 + 4 * akq + 2][am] = a1.z; As[n][16 + 4 * akq + 3][am] = a1.w;
    }
#pragma unroll
    for (int p = 0; p < PB; ++p) {
      int idx = tid + p * 256;
      int t4 = idx & (TQ - 1), k = idx / TQ;
      *(float4*)&Bs[k][4 * t4] = *(const float4*)&Xb[(size_t)(k0 + k) * T + t0 + 4 * t4];
    }
    __syncthreads();
#pragma unroll
    for (int kk = 0; kk < 32; ++kk) {
      float4 av[NOUT];
#pragma unroll
      for (int n = 0; n < NOUT; ++n) av[n] = *(const float4*)&As[n][kk][4 * ty];
      float4 bv[TN / 4];
#pragma unroll
      for (int g = 0; g < TN / 4; ++g) bv[g] = *(const float4*)&Bs[kk][4 * tx + 64 * g];
#pragma unroll
      for (int n = 0; n < NOUT; ++n) {
        const float a4[4] = {av[n].x, av[n].y, av[n].z, av[n].w};
#pragma unroll
        for (int i = 0; i < 4; ++i)
#pragma unroll
          for (int g = 0; g < TN / 4; ++g) {
            acc[n][i][4 * g + 0] += a4[i] * bv[g].x;
            acc[n][i][4 * g + 1] += a4[i] * bv[g].y;
            acc[n][i][4 * g + 2] += a4[i] * bv[g].z;
            acc[n][i][4 * g + 3] += a4[i] * bv[g].w;
          }
      }
    }
    __syncthreads();
  }
#pragma unroll
  for (int n = 0; n < NOUT; ++n) {
    float* Yn = (n == 0) ? Y0 : Y1;
    const float* bn = (n == 0) ? b0 : b1;
#pragma unroll
    for (int i = 0; i < 4; ++i) {
      int row = m0 + 4 * ty + i;
      float bi = bn[row];
#pragma unroll
      for (int g = 0; g < TN / 4; ++g) {
        float4 ov;
        ov.x = acc[n][i][4 * g + 0] + bi; ov.y = acc[n][i][4 * g + 1] + bi;
        ov.z = acc[n][i][4 * g + 2] + bi; ov.w = acc[n][i][4 * g + 3] + bi;
        *(float4*)&Yn[((size_t)b * 256 + row) * T + t0 + 4 * tx + 64 * g] = ov;
      }
    }
  }
}

// ---------------------------------------------------------------------------
// gemm_q_mfma (unchanged / passing): Q = Wq(bf16) @ x + bq, fused RoPE,
// out bf16 A-frags [bh][t][64].
// ---------------------------------------------------------------------------
__global__ __launch_bounds__(256, 2) void gemm_q_mfma(
    const short* __restrict__ wqbf, const float* __restrict__ bq,
    const float* __restrict__ X, short* __restrict__ qbf) {
  const int t0 = blockIdx.x * 64;
  const int b  = blockIdx.y;
  const int tid = threadIdx.x;
  const int w = tid >> 6, lane = tid & 63;
  const int quad = lane >> 4, l15 = lane & 15;

  __shared__ __align__(16) char smem[72704];
  float* Bsq = (float*)smem;          // [256k][68t] f32, col-XOR-swizzled
  float* Ep  = (float*)smem;          // [256row][71t] f32 (aliased post-loop)

  const float* xb = X + (size_t)b * CH * TTT + t0;
#pragma unroll
  for (int p = 0; p < 16; ++p) {
    int idx = tid + p * 256;
    int t4 = idx & 15, k = idx >> 4;
    int swz = ((k >> 3) & 3) * 16;
    *(float4*)&Bsq[k * 68 + ((4 * t4) ^ swz)] =
        *(const float4*)&xb[(size_t)k * TTT + 4 * t4];
  }
  __syncthreads();

  const int mbase = w * 64;
  f32x4 acc[4][4];
#pragma unroll
  for (int mf = 0; mf < 4; ++mf)
#pragma unroll
    for (int nt = 0; nt < 4; ++nt) acc[mf][nt] = (f32x4){0.f, 0.f, 0.f, 0.f};

#pragma unroll
  for (int k0 = 0; k0 < 256; k0 += 32) {
    bf16x8 bfr[4];
#pragma unroll
    for (int nt = 0; nt < 4; ++nt) {
      int col = (nt * 16 + l15) ^ (quad * 16);
      bf16x8 f;
#pragma unroll
      for (int j = 0; j < 8; ++j)
        f[j] = f2bf(Bsq[(k0 + quad * 8 + j) * 68 + col]);
      bfr[nt] = f;
    }
#pragma unroll
    for (int mf = 0; mf < 4; ++mf) {
      bf16x8 af = *(const bf16x8*)&wqbf[(size_t)(mbase + mf * 16 + l15) * 256 + k0 + quad * 8];
#pragma unroll
      for (int nt = 0; nt < 4; ++nt)
        acc[mf][nt] = __builtin_amdgcn_mfma_f32_16x16x32_bf16(af, bfr[nt], acc[mf][nt], 0, 0, 0);
    }
  }
  __syncthreads();   // all Bsq reads complete; alias as Ep

#pragma unroll
  for (int mf = 0; mf < 4; ++mf)
#pragma unroll
    for (int r = 0; r < 4; ++r) {
      int row = mbase + mf * 16 + quad * 4 + r;
      float bi = bq[row];
#pragma unroll
      for (int nt = 0; nt < 4; ++nt)
        Ep[row * 71 + nt * 16 + l15] = acc[mf][nt][r] + bi;
    }
  __syncthreads();

  const int tt = tid >> 2, cb = tid & 3;
  float sn[8], cs[8];
  const float tg = (float)(t0 + tt);
#pragma unroll
  for (int e = 0; e < 8; ++e) {
    float invr = __expf(-(float)(cb * 8 + e) * ROPE_C) * INV2PI;
    fast_sincos_rev(tg * invr, &sn[e], &cs[e]);
  }
#pragma unroll
  for (int hh = 0; hh < 4; ++hh) {
    float oa[8], oc[8];
#pragma unroll
    for (int e = 0; e < 8; ++e) {
      int j = cb * 8 + e;
      float a = Ep[(hh * 64 + j) * 71 + tt];
      float c = Ep[(hh * 64 + j + 32) * 71 + tt];
      oa[e] = a * cs[e] - c * sn[e];
      oc[e] = c * cs[e] + a * sn[e];
    }
    short* dst = qbf + ((size_t)(b * NH + hh) * TTT + t0 + tt) * 64 + cb * 8;
    *(uint4*)dst = make_uint4(pack2bf(oa[0], oa[1]), pack2bf(oa[2], oa[3]),
                              pack2bf(oa[4], oa[5]), pack2bf(oa[6], oa[7]));
    *(uint4*)(dst + 32) = make_uint4(pack2bf(oc[0], oc[1]), pack2bf(oc[2], oc[3]),
                                     pack2bf(oc[4], oc[5]), pack2bf(oc[6], oc[7]));
  }
}

// ---------------------------------------------------------------------------
// gemm_kv_mfma: K,V = Wkv(bf16) @ cond(bf16-staged) + b, MFMA core.
// Block = (64 s-cols, head, b), 4 waves: waves 0-1 -> 64 K-rows, 2-3 -> 64
// V-rows (32 rows each, acc 2x4 f32x4). cond tile [512k][64s] staged ONCE as
// bf16 LDS [512][68] (69.6 KB, no K-loop barriers); frag gather = 8 strided
// ds_read_u16 (stride-68: quads split {0,16} banks + l15 word-pairing ->
// <=2-way, free). A-frags direct from L2-hot bf16 weights. C/D (+bias) dump
// to aliased fp32 [128][68], then verified kvprep rope+transpose -> K
// [bh][s][64] and vectorized V [bh][ch][s]. Heads of one s-tile share an XCD
// (ids differ by 8) so the 4x cond re-read stays L2-resident.
// ---------------------------------------------------------------------------
__global__ __launch_bounds__(256, 2) void gemm_kv_mfma(
    const short* __restrict__ wkvbf,  // [512 rows][512 k]: 0-255 = K, 256-511 = V
    const float* __restrict__ bk2, const float* __restrict__ bv2,
    const float* __restrict__ X, short* __restrict__ kbf, short* __restrict__ vbf) {
  const int t0 = blockIdx.x * 64;
  const int hh = blockIdx.y;
  const int b  = blockIdx.z;
  const int tid = threadIdx.x;
  const int w = tid >> 6, lane = tid & 63;
  const int quad = lane >> 4, l15 = lane & 15;

  __shared__ __align__(16) char smem[69632];
  short* Ls = (short*)smem;       // [512 k][68 s] bf16
  float* Kv = (float*)smem;       // [128 row][68 s] f32 (epilogue alias)

  // ---- stage cond tile [512][64] -> bf16 LDS ----
  const float* Xb = X + (size_t)b * 512 * TSS + t0;
#pragma unroll
  for (int p = 0; p < 32; ++p) {
    int idx = tid + p * 256;          // 0..8191
    int s4 = idx & 15, k = idx >> 4;  // k 0..511
    float4 v = *(const float4*)&Xb[(size_t)k * TSS + 4 * s4];
    uint2 w2 = make_uint2(pack2bf(v.x, v.y), pack2bf(v.z, v.w));
    *(uint2*)&Ls[k * 68 + 4 * s4] = w2;
  }
  __syncthreads();

  const int isV = w >> 1;
  const int wbase = (w & 1) * 32;
  const short* wbf = wkvbf + (size_t)(isV * 256 + hh * 64 + wbase) * 512;
  const float* bias = isV ? bv2 : bk2;

  f32x4 acc[2][4];
#pragma unroll
  for (int mf = 0; mf < 2; ++mf)
#pragma unroll
    for (int nt = 0; nt < 4; ++nt) acc[mf][nt] = (f32x4){0.f, 0.f, 0.f, 0.f};

#pragma unroll
  for (int k0 = 0; k0 < 512; k0 += 32) {
    bf16x8 bfr[4];
#pragma unroll
    for (int nt = 0; nt < 4; ++nt) {
      int s = nt * 16 + l15;
      bf16x8 f;
#pragma unroll
      for (int j = 0; j < 8; ++j)
        f[j] = Ls[(k0 + quad * 8 + j) * 68 + s];
      bfr[nt] = f;
    }
#pragma unroll
    for (int mf = 0; mf < 2; ++mf) {
      bf16x8 af = *(const bf16x8*)&wbf[(size_t)(mf * 16 + l15) * 512 + k0 + quad * 8];
#pragma unroll
      for (int nt = 0; nt < 4; ++nt)
        acc[mf][nt] = __builtin_amdgcn_mfma_f32_16x16x32_bf16(af, bfr[nt], acc[mf][nt], 0, 0, 0);
    }
  }
  __syncthreads();   // all Ls reads done; alias as Kv

  // ---- C/D (+bias) -> Kv [128][68]: rows 0-63 = K, 64-127 = V ----
#pragma unroll
  for (int mf = 0; mf < 2; ++mf)
#pragma unroll
    for (int r = 0; r < 4; ++r) {
      int lr = wbase + mf * 16 + quad * 4 + r;   // 0..63 within K or V
      int ro = isV * 64 + lr;
      float bi = bias[hh * 64 + lr];
#pragma unroll
      for (int nt = 0; nt < 4; ++nt)
        Kv[ro * 68 + nt * 16 + l15] = acc[mf][nt][r] + bi;
    }
  __syncthreads();

  const int bh = b * NH + hh;

  // ---- V out: bf16 [bh][ch][s] ----
#pragma unroll
  for (int p = 0; p < 4; ++p) {
    int idx = tid + p * 256;          // 0..1023
    int s4 = idx & 15, ch = idx >> 4; // ch 0..63
    float4 v = *(const float4*)&Kv[(64 + ch) * 68 + 4 * s4];
    uint2 w2 = make_uint2(pack2bf(v.x, v.y), pack2bf(v.z, v.w));
    *(uint2*)&vbf[((size_t)bh * KC + ch) * TSS + t0 + 4 * s4] = w2;
  }

  // ---- K out: rope + transpose (verified kvprep pattern, stride 68) ----
  {
    int s = tid >> 2, g = tid & 3;
    float sg = (float)(t0 + s);
    unsigned ow[8];
#pragma unroll
    for (int hlf = 0; hlf < 8; ++hlf) {
      int ch = g * 16 + hlf * 2;
      float o2[2];
#pragma unroll
      for (int q = 0; q < 2; ++q) {
        int c = ch + q;
        int j = c & 31;
        float invr = __expf(-(float)j * ROPE_C) * INV2PI;
        float snv, csv;
        fast_sincos_rev(sg * invr, &snv, &csv);
        float a = Kv[c * 68 + s];
        float pv = Kv[(c ^ 32) * 68 + s];
        o2[q] = (c < 32) ? (a * csv - pv * snv) : (a * csv + pv * snv);
      }
      ow[hlf] = pack2bf(o2[0], o2[1]);
    }
    short* dst = kbf + ((size_t)bh * TSS + t0 + s) * 64 + g * 16;
    *(uint4*)dst = make_uint4(ow[0], ow[1], ow[2], ow[3]);
    *(uint4*)(dst + 8) = make_uint4(ow[4], ow[5], ow[6], ow[7]);
  }
}

// ---------------------------------------------------------------------------
// Bias folding (unchanged / passing)
// ---------------------------------------------------------------------------
__global__ __launch_bounds__(256) void bias_fold(
    const float* __restrict__ wk, const float* __restrict__ bk,
    const float* __restrict__ wv, const float* __restrict__ bv,
    const float* __restrict__ bcond,
    const float* __restrict__ wfilm, const float* __restrict__ bo,
    const float* __restrict__ bfilm,
    float* __restrict__ bk2, float* __restrict__ bv2, float* __restrict__ bf2) {
  int g = blockIdx.x * 256 + threadIdx.x;
  if (g < 256) {
    float s = bk[g];
    for (int k = 0; k < 256; ++k) s += wk[g * 256 + k] * bcond[k];
    bk2[g] = s;
  } else if (g < 512) {
    int m = g - 256;
    float s = bv[m];
    for (int k = 0; k < 256; ++k) s += wv[m * 256 + k] * bcond[k];
    bv2[m] = s;
  } else if (g < 1024) {
    int m = g - 512;
    float s = bfilm[m];
    for (int k = 0; k < 256; ++k) s += wfilm[m * 256 + k] * bo[k];
    bf2[m] = s;
  }
}

// ---------------------------------------------------------------------------
// fp32 -> bf16 bulk convert
// ---------------------------------------------------------------------------
__global__ __launch_bounds__(256) void cvt_bf16(
    const float* __restrict__ src, short* __restrict__ dst, int n) {
  int i = (blockIdx.x * 256 + threadIdx.x) * 8;
  if (i < n) {
    float4 a = *(const float4*)&src[i];
    float4 c = *(const float4*)&src[i + 4];
    uint4 w;
    w.x = pack2bf(a.x, a.y); w.y = pack2bf(a.z, a.w);
    w.z = pack2bf(c.x, c.y); w.w = pack2bf(c.z, c.w);
    *(uint4*)&dst[i] = w;
  }
}

// ---------------------------------------------------------------------------
// attn_mfma: r0 structure + direct pre-roped Q frags (measured 77 µs).
// ---------------------------------------------------------------------------
__global__ __launch_bounds__(256, 3) void attn_mfma(
    const short* __restrict__ qbf, const short* __restrict__ kbf,
    const short* __restrict__ vbf, const float* __restrict__ cond_mask,
    short* __restrict__ obuf) {
  const int t0 = blockIdx.x * 64;
  const int h = blockIdx.y, b = blockIdx.z;
  const int bh = b * NH + h;
  const int tid = threadIdx.x;
  const int w = tid >> 6, lane = tid & 63;
  const int quad = lane >> 4, l15 = lane & 15;

  __shared__ __align__(16) char smem[49152];
  short* Ks = (short*)smem;                 // 128x64 swizzled
  short* Vs = (short*)(smem + 16384);       // 64x128 swizzled
  short* Ps = (short*)(smem + 32768);       // 64x128 swizzled

  const short* qb = qbf + ((size_t)bh * TTT + t0) * 64;
  const int trow_l = w * 16 + l15;
  bf16x8 qf0 = *(const bf16x8*)&qb[(size_t)trow_l * 64 + quad * 8];
  bf16x8 qf1 = *(const bf16x8*)&qb[(size_t)trow_l * 64 + 32 + quad * 8];

  f32x4 acc_o[4];
#pragma unroll
  for (int n = 0; n < 4; ++n) acc_o[n] = (f32x4){0.f, 0.f, 0.f, 0.f};
  float den[4] = {0.f, 0.f, 0.f, 0.f};

  const float* cm = cond_mask + (size_t)b * TSS;
  const short* kbase = kbf + (size_t)bh * TSS * 64;
  const short* vbase = vbf + (size_t)bh * KC * TSS;

  for (int s0 = 0; s0 < TSS; s0 += 128) {
    __syncthreads();
#pragma unroll
    for (int p = 0; p < 4; ++p) {
      int idx = tid + p * 256;
      int blk = idx & 7, sr = idx >> 3;
      *(uint4*)&Ks[sr * 64 + 8 * (blk ^ (sr & 7))] =
          *(const uint4*)&kbase[(size_t)(s0 + sr) * 64 + 8 * blk];
    }
#pragma unroll
    for (int p = 0; p < 4; ++p) {
      int idx = tid + p * 256;
      int blk = idx & 15, ch = idx >> 4;
      *(uint4*)&Vs[ch * 128 + 8 * (blk ^ (ch & 7))] =
          *(const uint4*)&vbase[(size_t)ch * TSS + s0 + 8 * blk];
    }
    __syncthreads();

#pragma unroll
    for (int n0 = 0; n0 < 8; ++n0) {
      int srow = n0 * 16 + l15;
      bf16x8 kf0 = *(const bf16x8*)&Ks[srow * 64 + 8 * (quad ^ (srow & 7))];
      bf16x8 kf1 = *(const bf16x8*)&Ks[srow * 64 + 8 * ((4 + quad) ^ (srow & 7))];
      f32x4 acc = (f32x4){0.f, 0.f, 0.f, 0.f};
      acc = __builtin_amdgcn_mfma_f32_16x16x32_bf16(qf0, kf0, acc, 0, 0, 0);
      acc = __builtin_amdgcn_mfma_f32_16x16x32_bf16(qf1, kf1, acc, 0, 0, 0);
      float mk = (cm[s0 + srow] != 0.f) ? 1.f : 0.f;
      int sblk = n0 * 2 + (l15 >> 3);
      int slow = l15 & 7;
#pragma unroll
      for (int r = 0; r < 4; ++r) {
        float e = __expf(acc[r] * 0.125f) * mk;
        den[r] += e;
        int trow = w * 16 + quad * 4 + r;
        Ps[trow * 128 + 8 * (sblk ^ (trow & 7)) + slow] = f2bf(e);
      }
    }

    {
      int trow = w * 16 + l15;
#pragma unroll
      for (int kt = 0; kt < 4; ++kt) {
        bf16x8 pf = *(const bf16x8*)&Ps[trow * 128 + 8 * ((kt * 4 + quad) ^ (trow & 7))];
#pragma unroll
        for (int n0 = 0; n0 < 4; ++n0) {
          int ch = n0 * 16 + l15;
          bf16x8 vf = *(const bf16x8*)&Vs[ch * 128 + 8 * ((kt * 4 + quad) ^ (ch & 7))];
          acc_o[n0] = __builtin_amdgcn_mfma_f32_16x16x32_bf16(pf, vf, acc_o[n0], 0, 0, 0);
        }
      }
    }
  }

  float rd[4];
#pragma unroll
  for (int r = 0; r < 4; ++r) {
    float d = den[r];
#pragma unroll
    for (int off = 1; off < 16; off <<= 1) d += __shfl_xor(d, off, 16);
    rd[r] = 1.f / fmaxf(d, 1e-30f);
  }

  __syncthreads();
  short* Os = (short*)smem;
#pragma unroll
  for (int n0 = 0; n0 < 4; ++n0)
#pragma unroll
    for (int r = 0; r < 4; ++r) {
      int ch = n0 * 16 + l15;
      int trow = w * 16 + quad * 4 + r;
      Os[trow * 64 + ch] = f2bf(acc_o[n0][r] * rd[r]);
    }
  __syncthreads();

  short* ob = obuf + ((size_t)b * TTT + t0) * CH + h * KC;
#pragma unroll
  for (int p = 0; p < 2; ++p) {
    int idx = tid + p * 256;
    int t = idx >> 3, c8 = idx & 7;
    *(uint4*)&ob[(size_t)t * CH + c8 * 8] = *(const uint4*)&Os[t * 64 + c8 * 8];
  }
}

// ---------------------------------------------------------------------------
// film_mfma (unchanged / passing)
// ---------------------------------------------------------------------------
__global__ __launch_bounds__(256) void film_mfma(
    const short* __restrict__ wfbf, const float* __restrict__ bf2,
    const short* __restrict__ ybf, const float* __restrict__ X,
    const float* __restrict__ xmask, float* __restrict__ out) {
  const int t0 = blockIdx.x * 64;
  const int b = blockIdx.y;
  const int tid = threadIdx.x;
  const int w = tid >> 6, lane = tid & 63;
  const int quad = lane >> 4, l15 = lane & 15;

  __shared__ __align__(16) short Ys[64 * 256];

  const short* yb = ybf + ((size_t)b * TTT + t0) * CH;
#pragma unroll
  for (int p = 0; p < 8; ++p) {
    int idx = tid + p * 256;
    int cb = idx & 31, tr = idx >> 5;
    *(uint4*)&Ys[tr * 256 + 8 * (cb ^ (tr & 7))] =
        *(const uint4*)&yb[(size_t)tr * CH + 8 * cb];
  }
  __syncthreads();

  const int mbase = w * 64;
  f32x4 accg[4][4], accb[4][4];
#pragma unroll
  for (int mf = 0; mf < 4; ++mf)
#pragma unroll
    for (int nt = 0; nt < 4; ++nt) {
      accg[mf][nt] = (f32x4){0.f, 0.f, 0.f, 0.f};
      accb[mf][nt] = (f32x4){0.f, 0.f, 0.f, 0.f};
    }

#pragma unroll
  for (int k0 = 0; k0 < 256; k0 += 32) {
    const int cb0 = (k0 >> 3) + quad;
    bf16x8 bfr[4];
#pragma unroll
    for (int nt = 0; nt < 4; ++nt) {
      int tr = nt * 16 + l15;
      bfr[nt] = *(const bf16x8*)&Ys[tr * 256 + 8 * (cb0 ^ (tr & 7))];
    }
#pragma unroll
    for (int mf = 0; mf < 4; ++mf) {
      int rowg = mbase + mf * 16 + l15;
      bf16x8 ag = *(const bf16x8*)&wfbf[(size_t)rowg * 256 + k0 + quad * 8];
      bf16x8 ab = *(const bf16x8*)&wfbf[(size_t)(256 + rowg) * 256 + k0 + quad * 8];
#pragma unroll
      for (int nt = 0; nt < 4; ++nt) {
        accg[mf][nt] = __builtin_amdgcn_mfma_f32_16x16x32_bf16(ag, bfr[nt], accg[mf][nt], 0, 0, 0);
        accb[mf][nt] = __builtin_amdgcn_mfma_f32_16x16x32_bf16(ab, bfr[nt], accb[mf][nt], 0, 0, 0);
      }
    }
  }

  const float* xb = X + (size_t)b * CH * TTT + t0;
  const float* xm = xmask + (size_t)b * TTT + t0;
  float* ob = out + (size_t)b * CH * TTT + t0;
  float xmv[4];
#pragma unroll
  for (int nt = 0; nt < 4; ++nt) xmv[nt] = xm[nt * 16 + l15];

#pragma unroll
  for (int mf = 0; mf < 4; ++mf) {
#pragma unroll
    for (int r = 0; r < 4; ++r) {
      int row = mbase + mf * 16 + quad * 4 + r;
      float bg = bf2[row];
      float bb = bf2[256 + row];
#pragma unroll
      for (int nt = 0; nt < 4; ++nt) {
        int t = nt * 16 + l15;
        float g  = accg[mf][nt][r] + bg;
        float bt = accb[mf][nt][r] + bb;
        float xv = xb[(size_t)row * TTT + t];
        ob[(size_t)row * TTT + t] = (xv * g + bt) * xmv[nt];
      }
    }
  }
}

// ---------------------------------------------------------------------------
extern "C" void kernel_launch(void* const* d_in, const int* in_sizes, int n_in,
                              void* d_out, int out_size, void* d_ws, size_t ws_size,
                              hipStream_t stream) {
  const float* x           = (const float*)d_in[0];
  const float* x_mask      = (const float*)d_in[1];
  const float* cond_latent = (const float*)d_in[2];
  const float* cond_mask   = (const float*)d_in[3];
  const float* w_cond      = (const float*)d_in[4];
  const float* b_cond      = (const float*)d_in[5];
  const float* wq          = (const float*)d_in[6];
  const float* bq          = (const float*)d_in[7];
  const float* wk          = (const float*)d_in[8];
  const float* bk          = (const float*)d_in[9];
  const float* wv          = (const float*)d_in[10];
  const float* bv          = (const float*)d_in[11];
  const float* wo          = (const float*)d_in[12];
  const float* bo          = (const float*)d_in[13];
  const float* w_film      = (const float*)d_in[14];
  const float* b_film      = (const float*)d_in[15];
  float* out = (float*)d_out;

  float* ws = (float*)d_ws;
  float* k_buf = ws;                    // (region reused by o_bf)
  float* v_buf = k_buf + 2097152;
  float* wk2   = v_buf + 2097152;       // 131,072 (wk2 || wv2 contiguous)
  float* wv2   = wk2 + 131072;          // 131,072
  float* wf2   = wv2 + 131072;          // 131,072
  float* bk2   = wf2 + 131072;          // 256
  float* bv2   = bk2 + 256;             // 256
  float* bf2   = bv2 + 256;             // 512
  float* zbuf  = bf2 + 512;             // 512 zeros
  short* k_bf  = (short*)(zbuf + 512);  // 16*4*512*64 bf16
  short* v_bf  = k_bf + 2097152;        // 16*4*64*512 bf16
  short* wf2bf = v_bf + 2097152;        // 512*256 bf16
  short* q_bf  = wf2bf + 131072;        // 16*4*2048*64 bf16
  short* wq_bf = q_bf + 8388608;        // 256*256 bf16
  short* wkv_bf = wq_bf + 65536;        // 512*512 bf16 (K rows || V rows)
  short* o_bf  = (short*)k_buf;         // 16*2048*256 bf16 (aliases k/v_buf)

  dim3 blk(256);

  hipMemsetAsync(zbuf, 0, 512 * sizeof(float), stream);

  // --- weight folding + casts ---
  cvt_bf16<<<dim3(32), blk, 0, stream>>>(wq, wq_bf, 65536);
  gemm_v2<4, 2><<<dim3(8, 4, 1), blk, 0, stream>>>(
      wk, zbuf, wv, zbuf, w_cond, wk2, wv2, 256, 512);
  gemm_v2<4, 1><<<dim3(4, 8, 1), blk, 0, stream>>>(
      w_film, zbuf, nullptr, nullptr, wo, wf2, nullptr, 256, 256);
  cvt_bf16<<<dim3(128), blk, 0, stream>>>(wk2, wkv_bf, 262144);  // wk2||wv2
  cvt_bf16<<<dim3(64), blk, 0, stream>>>(wf2, wf2bf, 131072);
  bias_fold<<<dim3(4), blk, 0, stream>>>(wk, bk, wv, bv, b_cond,
                                         w_film, bo, b_film, bk2, bv2, bf2);

  // --- main pipeline ---
  // Q projection on MFMA with fused RoPE + bf16 + transpose
  gemm_q_mfma<<<dim3(32, 16), blk, 0, stream>>>(wq_bf, bq, x, q_bf);
  // K/V projection on MFMA with fused rope/bf16 epilogues
  gemm_kv_mfma<<<dim3(8, 4, 16), blk, 0, stream>>>(
      wkv_bf, bk2, bv2, cond_latent, k_bf, v_bf);
  // MFMA attention (r0 structure, 64 t/block)
  attn_mfma<<<dim3(32, 4, 16), blk, 0, stream>>>(q_bf, k_bf, v_bf, cond_mask, o_bf);
  // MFMA film + final output
  film_mfma<<<dim3(32, 16), blk, 0, stream>>>(wf2bf, bf2, o_bf, x, x_mask, out);
}